// Round 7
// baseline (4672.217 us; speedup 1.0000x reference)
//
#include <hip/hip_runtime.h>
#include <hip/hip_bf16.h>

typedef __hip_bfloat16 bf16;

#define ROWS 8192   // B*N
#define NPTS 2048
#define CIN  128
#define COUT 256
#define KNN  32
#define PAD  132    // 16-row LDS tile leading dim (132%32=4 -> 2-way max, free)

__device__ inline float lrelu(float x){ return x >= 0.f ? x : 0.2f*x; }

// ---------------- weight packing: Wcat[128][2048] = [q0|k0|v0|r0|q1|k1|v1|r1] ----------------
__global__ __launch_bounds__(256) void pack_w_kernel(
    const float* qW, const float* kW, const float* vW, const float* rW,
    const float* qb, const float* kb, const float* vb, const float* rb,
    float* Wcat, float* bcat){
  int t = blockIdx.x*256 + threadIdx.x;     // 0 .. 128*2048-1
  int r = t >> 11, c = t & 2047;
  int g = c >> 8, i = g >> 2, tt = g & 3, cc = c & 255;
  const float* W = (tt==0?qW: tt==1?kW: tt==2?vW: rW) + (size_t)i*CIN*COUT;
  Wcat[t] = W[r*COUT + cc];
  if (r == 0){
    const float* bb = (tt==0?qb: tt==1?kb: tt==2?vb: rb) + i*COUT;
    bcat[c] = bb[cc];
  }
}

// ---------------- serial top-32 on fp32 (lane 0): strict-< keeps lowest index on ties ----------------
__device__ void topk32_f32(const float* drow, int* out){
  float bd[KNN]; int bi[KNN];
  int cnt = 0;
  float worst = 3.4e38f;
  for (int m = 0; m < NPTS; ++m){
    float v = drow[m];
    if (cnt < KNN){
      int j = cnt++;
      while (j > 0 && bd[j-1] > v){ bd[j]=bd[j-1]; bi[j]=bi[j-1]; --j; }
      bd[j]=v; bi[j]=m;
      worst = bd[cnt-1];
    } else if (v < worst){
      int j = KNN-1;
      while (j > 0 && bd[j-1] > v){ bd[j]=bd[j-1]; bi[j]=bi[j-1]; --j; }
      bd[j]=v; bi[j]=m;
      worst = bd[KNN-1];
    }
  }
  for (int j = 0; j < KNN; ++j) out[j] = bi[j];
}

// ---------------- xyz KNN: numpy scalar path (C=3 < vstep): mul+add, no FMA ----------------
__global__ __launch_bounds__(64) void knn_xyz_kernel(const float* xyz, const float* base, int* idx_out){
  __shared__ float drow[NPTS];
  int bid = blockIdx.x;           // b*2048+n
  int b = bid >> 11;
  int lane = threadIdx.x;
  float q0 = xyz[(size_t)bid*3+0];
  float q1 = xyz[(size_t)bid*3+1];
  float q2 = xyz[(size_t)bid*3+2];
  // np.sum(src*src,-1), n=3<8 naive on the product temp: ((q0^2)+q1^2)+q2^2
  float qq = __fadd_rn(__fadd_rn(__fmul_rn(q0,q0), __fmul_rn(q1,q1)), __fmul_rn(q2,q2));
  const float* bb = base + (size_t)b*NPTS*3;
  for (int m = lane; m < NPTS; m += 64){
    float p0 = bb[m*3+0], p1 = bb[m*3+1], p2 = bb[m*3+2];
    float pp = __fadd_rn(__fadd_rn(__fmul_rn(p0,p0), __fmul_rn(p1,p1)), __fmul_rn(p2,p2));
    // einsum scalar tail: accum += a*b (ISO C, no contraction)
    float dot = __fmul_rn(q0,p0);
    dot = __fadd_rn(dot, __fmul_rn(q1,p1));
    dot = __fadd_rn(dot, __fmul_rn(q2,p2));
    drow[m] = __fsub_rn(__fadd_rn(qq, pp), __fmul_rn(2.f, dot));
  }
  __syncthreads();
  if (lane == 0) topk32_f32(drow, idx_out + (size_t)bid*KNN);
}

// ---------------- feature norms: numpy SIMD pairwise block (AVX512, 8 vec accumulators) ----------------
__global__ __launch_bounds__(256) void rownorm_kernel(const float* feat, float* nrm){
  int row = blockIdx.x*256 + threadIdx.x;
  const float* f = feat + (size_t)row*CIN;
  float L[16];
  #pragma unroll
  for (int l = 0; l < 16; ++l){
    float x0 = __fmul_rn(f[l],     f[l]);
    float x1 = __fmul_rn(f[16+l],  f[16+l]);
    float x2 = __fmul_rn(f[32+l],  f[32+l]);
    float x3 = __fmul_rn(f[48+l],  f[48+l]);
    float x4 = __fmul_rn(f[64+l],  f[64+l]);
    float x5 = __fmul_rn(f[80+l],  f[80+l]);
    float x6 = __fmul_rn(f[96+l],  f[96+l]);
    float x7 = __fmul_rn(f[112+l], f[112+l]);
    // ((r0+r1)+(r2+r3)) + ((r4+r5)+(r6+r7)) per lane
    L[l] = __fadd_rn(
        __fadd_rn(__fadd_rn(x0,x1), __fadd_rn(x2,x3)),
        __fadd_rn(__fadd_rn(x4,x5), __fadd_rn(x6,x7)));
  }
  // npyv_sum_f32 (AVX512) horizontal tree
  float T2[4];
  #pragma unroll
  for (int i = 0; i < 4; ++i)
    T2[i] = __fadd_rn(__fadd_rn(L[i], L[i+8]), __fadd_rn(L[i+4], L[i+12]));
  nrm[row] = __fadd_rn(__fadd_rn(T2[0], T2[2]), __fadd_rn(T2[1], T2[3]));
}

// ---------------- feature self-distance: numpy einsum contig_outstride0_two, AVX512 ----------------
// per lane l: chained FMA over k = 48,32,16,0,112,96,80,64 (+l); horizontal npyv_sum tree.
__global__ __launch_bounds__(256) void dist_feat_kernel(const float* fb, const float* nrm, float* D){
  __shared__ float Aq[16*PAD];
  __shared__ float Bm[16*PAD];
  int nb = blockIdx.y*16, mb = blockIdx.x*16;
  int t = threadIdx.x;
  {
    int r = t >> 4, seg = (t & 15) << 3;
    const float* an = fb + (size_t)(nb + r)*CIN + seg;
    const float* bm = fb + (size_t)(mb + r)*CIN + seg;
    #pragma unroll
    for (int j = 0; j < 8; ++j){ Aq[r*PAD + seg + j] = an[j]; Bm[r*PAD + seg + j] = bm[j]; }
  }
  __syncthreads();
  int ty = t >> 4, tx = t & 15;
  const float* qa = &Aq[ty*PAD];
  const float* ma = &Bm[tx*PAD];
  float P[16];
  #pragma unroll
  for (int l = 0; l < 16; ++l) P[l] = __fmul_rn(qa[48+l], ma[48+l]);   // fma(a3,b3,0)
  #pragma unroll
  for (int l = 0; l < 16; ++l) P[l] = __fmaf_rn(qa[32+l], ma[32+l], P[l]);
  #pragma unroll
  for (int l = 0; l < 16; ++l) P[l] = __fmaf_rn(qa[16+l], ma[16+l], P[l]);
  #pragma unroll
  for (int l = 0; l < 16; ++l) P[l] = __fmaf_rn(qa[ 0+l], ma[ 0+l], P[l]);
  #pragma unroll
  for (int l = 0; l < 16; ++l) P[l] = __fmaf_rn(qa[112+l], ma[112+l], P[l]);
  #pragma unroll
  for (int l = 0; l < 16; ++l) P[l] = __fmaf_rn(qa[96+l], ma[96+l], P[l]);
  #pragma unroll
  for (int l = 0; l < 16; ++l) P[l] = __fmaf_rn(qa[80+l], ma[80+l], P[l]);
  #pragma unroll
  for (int l = 0; l < 16; ++l) P[l] = __fmaf_rn(qa[64+l], ma[64+l], P[l]);
  float T2[4];
  #pragma unroll
  for (int i = 0; i < 4; ++i)
    T2[i] = __fadd_rn(__fadd_rn(P[i], P[i+8]), __fadd_rn(P[i+4], P[i+12]));
  float dot = __fadd_rn(__fadd_rn(T2[0], T2[2]), __fadd_rn(T2[1], T2[3]));
  int n = nb + ty, m = mb + tx;
  D[(size_t)n*NPTS + m] = __fsub_rn(__fadd_rn(nrm[n], nrm[m]), __fmul_rn(2.f, dot));
}

__global__ __launch_bounds__(64) void topk_row_kernel(const float* D, int* idx_out){
  __shared__ float drow[NPTS];
  int n = blockIdx.x;
  const float* src = D + (size_t)n*NPTS;
  for (int m = threadIdx.x; m < NPTS; m += 64) drow[m] = src[m];
  __syncthreads();
  if (threadIdx.x == 0) topk32_f32(drow, idx_out + (size_t)n*KNN);
}

// ---------------- generic tiled GEMM: C[*,N] = A[*,K] @ B[K,N] + bias[N], fp32 acc ----------------
__global__ __launch_bounds__(256) void gemm_tiled(const float* A, int lda, const float* B, int ldb,
                                                  const float* bias, float* C, int ldc, int K){
  __shared__ float As[64*17];
  __shared__ float Bs[16*65];
  int nb = blockIdx.x*64, mb = blockIdx.y*64;
  int tx = threadIdx.x & 15, ty = threadIdx.x >> 4;
  float acc[4][4] = {};
  for (int kt = 0; kt < K; kt += 16){
    {
      int r = threadIdx.x >> 2, c4 = (threadIdx.x & 3) << 2;
      const float* ap = A + (size_t)(mb + r)*lda + kt + c4;
      #pragma unroll
      for (int j = 0; j < 4; ++j) As[r*17+c4+j] = ap[j];
    }
    {
      int r = threadIdx.x >> 4, c4 = (threadIdx.x & 15) << 2;
      const float* bp = B + (size_t)(kt + r)*ldb + nb + c4;
      #pragma unroll
      for (int j = 0; j < 4; ++j) Bs[r*65+c4+j] = bp[j];
    }
    __syncthreads();
    #pragma unroll
    for (int kk = 0; kk < 16; ++kk){
      float a[4], bv[4];
      #pragma unroll
      for (int i = 0; i < 4; ++i) a[i] = As[(ty*4+i)*17+kk];
      #pragma unroll
      for (int j = 0; j < 4; ++j) bv[j] = Bs[kk*65 + tx*4 + j];
      #pragma unroll
      for (int i = 0; i < 4; ++i)
        #pragma unroll
        for (int j = 0; j < 4; ++j) acc[i][j] += a[i]*bv[j];
    }
    __syncthreads();
  }
  #pragma unroll
  for (int i = 0; i < 4; ++i){
    int row = mb + ty*4 + i;
    #pragma unroll
    for (int j = 0; j < 4; ++j){
      int col = nb + tx*4 + j;
      C[(size_t)row*ldc + col] = acc[i][j] + bias[col];
    }
  }
}

// ---------------- attention for one branch: Xb[8192][1024] = [q|k|v|res] fp32 ----------------
__global__ __launch_bounds__(256) void attn_kernel(const float* Xb, const int* ip, float* ctx){
  int bn = blockIdx.x;
  int b  = bn >> 11;
  int c  = threadIdx.x;
  __shared__ int jr[KNN];
  if (c < KNN) jr[c] = (b << 11) + ip[(size_t)bn*KNN + c];
  __syncthreads();
  float qv = Xb[(size_t)bn*1024 + c];
  float e[KNN];
  float mx = -3.4e38f;
  #pragma unroll
  for (int k = 0; k < KNN; ++k){
    float kv = Xb[(size_t)jr[k]*1024 + 256 + c];
    e[k] = (qv - kv) * 0.0625f;     // / sqrt(256)
    mx = fmaxf(mx, e[k]);
  }
  float s = 0.f;
  #pragma unroll
  for (int k = 0; k < KNN; ++k) s += __expf(e[k] - mx);
  float inv = 1.f / s;
  float best = -3.4e38f;
  #pragma unroll
  for (int k = 0; k < KNN; ++k){
    float vv  = Xb[(size_t)jr[k]*1024 + 512 + c];
    float att = __expf(e[k] - mx)*inv - 1.0f;   // softmax minus its (==1) sum
    best = fmaxf(best, att*vv);
  }
  ctx[(size_t)bn*COUT + c] = best;
}

// ---------------- BatchNorm stats (deterministic two-stage) ----------------
__global__ __launch_bounds__(256) void bn_stats_partial(const float* Xp, int ld, float* partial){
  int p = blockIdx.x, c = threadIdx.x;
  float s = 0.f, s2 = 0.f;
  for (int r = 0; r < 256; ++r){
    float v = Xp[(size_t)(p*256 + r)*ld + c];
    s += v; s2 += v*v;
  }
  partial[p*512 + c]       = s;
  partial[p*512 + 256 + c] = s2;
}

__global__ __launch_bounds__(256) void bn_stats_final(const float* partial, float* stats){
  int c = threadIdx.x;
  float s = 0.f, s2 = 0.f;
  for (int p = 0; p < 32; ++p){ s += partial[p*512 + c]; s2 += partial[p*512 + 256 + c]; }
  float mean = s * (1.f/8192.f);
  float var  = s2 * (1.f/8192.f) - mean*mean;   // biased var
  stats[c]       = mean;
  stats[256 + c] = 1.f / sqrtf(var + 1e-5f);
}

// ---------------- m_i = leaky(bn_res(res)) + leaky(bn_ffn(F)); write Mmat[:, i*256:] ----------------
__global__ __launch_bounds__(256) void build_m_kernel(const float* Xb, const float* F,
    const float* sR, const float* sF,
    const float* gR, const float* bR, const float* gF, const float* bF,
    float* Mcol){
  int bn = blockIdx.x, c = threadIdx.x;
  float r  = Xb[(size_t)bn*1024 + 768 + c];
  float rv = gR[c] * (r - sR[c]) * sR[256+c] + bR[c];
  rv = lrelu(rv);
  float f  = F[(size_t)bn*COUT + c];
  float fv = gF[c] * (f - sF[c]) * sF[256+c] + bF[c];
  fv = lrelu(fv);
  Mcol[(size_t)bn*512 + c] = rv + fv;
}

__global__ __launch_bounds__(256) void final_kernel(const float* Y, const float* stats,
                                                    const float* g, const float* be, float* out){
  int bn = blockIdx.x, c = threadIdx.x;
  float y = Y[(size_t)bn*COUT + c];
  float v = g[c] * (y - stats[c]) * stats[256+c] + be[c];
  out[(size_t)bn*COUT + c] = lrelu(v);   // fp32 output
}

extern "C" void kernel_launch(void* const* d_in, const int* in_sizes, int n_in,
                              void* d_out, int out_size, void* d_ws, size_t ws_size,
                              hipStream_t stream){
  const float* xyz      = (const float*)d_in[0];
  const float* base_xyz = (const float*)d_in[1];
  const float* feature  = (const float*)d_in[2];
  const float* qW = (const float*)d_in[3];
  const float* qb = (const float*)d_in[4];
  const float* kW = (const float*)d_in[5];
  const float* kb = (const float*)d_in[6];
  const float* vW = (const float*)d_in[7];
  const float* vb = (const float*)d_in[8];
  const float* rW = (const float*)d_in[9];
  const float* rb = (const float*)d_in[10];
  const float* res_gamma = (const float*)d_in[11];
  const float* res_beta  = (const float*)d_in[12];
  const float* ffnW = (const float*)d_in[13];
  const float* ffnb = (const float*)d_in[14];
  const float* ffn_gamma = (const float*)d_in[15];
  const float* ffn_beta  = (const float*)d_in[16];
  const float* fcW = (const float*)d_in[17];
  const float* fcb = (const float*)d_in[18];
  const float* fc_gamma = (const float*)d_in[19];
  const float* fc_beta  = (const float*)d_in[20];
  float* out = (float*)d_out;

  // ---- workspace plan (~67 MB) ----
  char* ws = (char*)d_ws;
  size_t o = 0;
  auto alloc = [&](size_t bytes)->char*{
    char* p = ws + o;
    o += (bytes + 255) & ~(size_t)255;
    return p;
  };
  int*   idx0   = (int*)  alloc((size_t)ROWS*KNN*4);        // 1 MB
  int*   idx1   = (int*)  alloc((size_t)ROWS*KNN*4);        // 1 MB
  float* nrm    = (float*)alloc((size_t)ROWS*4);            // 32 KB
  float* Wcat   = (float*)alloc((size_t)CIN*2048*4);        // 1 MB
  float* bcat   = (float*)alloc((size_t)2048*4);            // 8 KB
  float* stats  = (float*)alloc((size_t)5*512*4);
  float* partial= (float*)alloc((size_t)32*512*4);
  char*  R1     = alloc((size_t)ROWS*1024*4);               // 32 MB: Dbuf (16MB) -> Xb fp32
  float* Mmat   = (float*)alloc((size_t)ROWS*512*4);        // 16 MB
  char*  R3     = alloc((size_t)ROWS*COUT*4);               //  8 MB: ctx -> Y
  float* F      = (float*)alloc((size_t)ROWS*COUT*4);       //  8 MB
  float* Dbuf = (float*)R1;
  float* Xb   = (float*)R1;
  float* ctx  = (float*)R3;
  float* Y    = (float*)R3;

  pack_w_kernel<<<(CIN*2048)/256, 256, 0, stream>>>(qW,kW,vW,rW,qb,kb,vb,rb,Wcat,bcat);
  knn_xyz_kernel<<<ROWS, 64, 0, stream>>>(xyz, base_xyz, idx0);
  rownorm_kernel<<<ROWS/256, 256, 0, stream>>>(feature, nrm);

  // per-batch feature-distance (numpy AVX512-faithful fp32) + top-k
  for (int b = 0; b < 4; ++b){
    const float* fb = feature + (size_t)b*NPTS*CIN;
    dist_feat_kernel<<<dim3(NPTS/16, NPTS/16), 256, 0, stream>>>(
        fb, nrm + (size_t)b*NPTS, Dbuf);
    topk_row_kernel<<<NPTS, 64, 0, stream>>>(Dbuf, idx1 + (size_t)b*NPTS*KNN);
  }

  // two transformer branches, sequential (Xb/ctx/F regions reused)
  for (int i = 0; i < 2; ++i){
    gemm_tiled<<<dim3(1024/64, ROWS/64), 256, 0, stream>>>(
        feature, CIN, Wcat + (size_t)i*1024, 2048, bcat + (size_t)i*1024, Xb, 1024, CIN);

    attn_kernel<<<ROWS, 256, 0, stream>>>(Xb, (i == 0 ? idx0 : idx1), ctx);

    bn_stats_partial<<<32, 256, 0, stream>>>(Xb + 768, 1024, partial);
    bn_stats_final<<<1, 256, 0, stream>>>(partial, stats + (size_t)i*512);

    gemm_tiled<<<dim3(COUT/64, ROWS/64), 256, 0, stream>>>(
        ctx, COUT, ffnW + (size_t)i*COUT*COUT, COUT, ffnb + (size_t)i*COUT, F, COUT, COUT);
    bn_stats_partial<<<32, 256, 0, stream>>>(F, COUT, partial);
    bn_stats_final<<<1, 256, 0, stream>>>(partial, stats + (size_t)(2+i)*512);

    build_m_kernel<<<ROWS, 256, 0, stream>>>(Xb, F,
        stats + (size_t)i*512, stats + (size_t)(2+i)*512,
        res_gamma + (size_t)i*COUT, res_beta + (size_t)i*COUT,
        ffn_gamma + (size_t)i*COUT, ffn_beta + (size_t)i*COUT,
        Mmat + (size_t)i*COUT);
  }

  // fc: Y = Mmat[8192][512] @ fcW[512][256] + fcb
  gemm_tiled<<<dim3(COUT/64, ROWS/64), 256, 0, stream>>>(
      Mmat, 512, fcW, COUT, fcb, Y, COUT, 512);
  bn_stats_partial<<<32, 256, 0, stream>>>(Y, COUT, partial);
  bn_stats_final<<<1, 256, 0, stream>>>(partial, stats + 4*512);

  final_kernel<<<ROWS, 256, 0, stream>>>(Y, stats + 4*512, fc_gamma, fc_beta, out);
}

// Round 8
// 1024.616 us; speedup vs baseline: 4.5600x; 4.5600x over previous
//
#include <hip/hip_runtime.h>
#include <hip/hip_bf16.h>

typedef __hip_bfloat16 bf16;

#define ROWS 8192   // B*N
#define NPTS 2048
#define CIN  128
#define COUT 256
#define KNN  32
#define PAD  132    // 16-row LDS tile leading dim (132%32=4 -> 2-way max, free)

__device__ inline float lrelu(float x){ return x >= 0.f ? x : 0.2f*x; }

// ---------------- weight packing: Wcat[128][2048] = [q0|k0|v0|r0|q1|k1|v1|r1] ----------------
__global__ __launch_bounds__(256) void pack_w_kernel(
    const float* qW, const float* kW, const float* vW, const float* rW,
    const float* qb, const float* kb, const float* vb, const float* rb,
    float* Wcat, float* bcat){
  int t = blockIdx.x*256 + threadIdx.x;     // 0 .. 128*2048-1
  int r = t >> 11, c = t & 2047;
  int g = c >> 8, i = g >> 2, tt = g & 3, cc = c & 255;
  const float* W = (tt==0?qW: tt==1?kW: tt==2?vW: rW) + (size_t)i*CIN*COUT;
  Wcat[t] = W[r*COUT + cc];
  if (r == 0){
    const float* bb = (tt==0?qb: tt==1?kb: tt==2?vb: rb) + i*COUT;
    bcat[c] = bb[cc];
  }
}

// ---------------- wave-parallel top-32: keys in registers, no scratch ----------------
// key = monotone-uint(d) << 32 | m  -> lexicographic (d, idx) min == lax.top_k tie semantics
__device__ inline unsigned long long dist_key(float d, int m){
  unsigned u = __float_as_uint(d);
  u = (u & 0x80000000u) ? ~u : (u | 0x80000000u);
  return ((unsigned long long)u << 32) | (unsigned)m;
}

__device__ inline void wave_topk32(unsigned long long* k64, int lane, int* out){
  for (int r = 0; r < KNN; ++r){
    // local tournament min over this lane's 32 keys (fully unrolled, registers only)
    unsigned long long m = k64[0];
    #pragma unroll
    for (int j = 1; j < 32; ++j) m = (k64[j] < m) ? k64[j] : m;
    // 64-lane butterfly min
    #pragma unroll
    for (int s = 1; s < 64; s <<= 1){
      unsigned long long o = __shfl_xor(m, s, 64);
      m = (o < m) ? o : m;
    }
    int wm = (int)(unsigned)(m & 0xFFFFFFFFu);
    if ((wm & 63) == lane){
      int jw = wm >> 6;
      #pragma unroll
      for (int j = 0; j < 32; ++j) if (j == jw) k64[j] = ~0ull;  // remove winner (cndmask, no scratch)
    }
    if (lane == 0) out[r] = wm;
  }
}

// ---------------- xyz KNN: numpy scalar path (C=3 < vstep): mul+add, no FMA ----------------
__global__ __launch_bounds__(64) void knn_xyz_kernel(const float* xyz, const float* base, int* idx_out){
  __shared__ float drow[NPTS];
  int bid = blockIdx.x;           // b*2048+n
  int b = bid >> 11;
  int lane = threadIdx.x;
  float q0 = xyz[(size_t)bid*3+0];
  float q1 = xyz[(size_t)bid*3+1];
  float q2 = xyz[(size_t)bid*3+2];
  // np.sum(src*src,-1), n=3<8 naive on the product temp: ((q0^2)+q1^2)+q2^2
  float qq = __fadd_rn(__fadd_rn(__fmul_rn(q0,q0), __fmul_rn(q1,q1)), __fmul_rn(q2,q2));
  const float* bb = base + (size_t)b*NPTS*3;
  for (int m = lane; m < NPTS; m += 64){
    float p0 = bb[m*3+0], p1 = bb[m*3+1], p2 = bb[m*3+2];
    float pp = __fadd_rn(__fadd_rn(__fmul_rn(p0,p0), __fmul_rn(p1,p1)), __fmul_rn(p2,p2));
    // einsum scalar tail: accum += a*b (ISO C, no contraction)
    float dot = __fmul_rn(q0,p0);
    dot = __fadd_rn(dot, __fmul_rn(q1,p1));
    dot = __fadd_rn(dot, __fmul_rn(q2,p2));
    drow[m] = __fsub_rn(__fadd_rn(qq, pp), __fmul_rn(2.f, dot));
  }
  __syncthreads();
  unsigned long long k64[32];
  #pragma unroll
  for (int i = 0; i < 32; ++i){
    int m = i*64 + lane;
    k64[i] = dist_key(drow[m], m);
  }
  wave_topk32(k64, lane, idx_out + (size_t)bid*KNN);
}

// ---------------- feature norms: numpy SIMD pairwise block (AVX512, 8 vec accumulators) ----------------
__global__ __launch_bounds__(256) void rownorm_kernel(const float* feat, float* nrm){
  int row = blockIdx.x*256 + threadIdx.x;
  const float* f = feat + (size_t)row*CIN;
  float L[16];
  #pragma unroll
  for (int l = 0; l < 16; ++l){
    float x0 = __fmul_rn(f[l],     f[l]);
    float x1 = __fmul_rn(f[16+l],  f[16+l]);
    float x2 = __fmul_rn(f[32+l],  f[32+l]);
    float x3 = __fmul_rn(f[48+l],  f[48+l]);
    float x4 = __fmul_rn(f[64+l],  f[64+l]);
    float x5 = __fmul_rn(f[80+l],  f[80+l]);
    float x6 = __fmul_rn(f[96+l],  f[96+l]);
    float x7 = __fmul_rn(f[112+l], f[112+l]);
    L[l] = __fadd_rn(
        __fadd_rn(__fadd_rn(x0,x1), __fadd_rn(x2,x3)),
        __fadd_rn(__fadd_rn(x4,x5), __fadd_rn(x6,x7)));
  }
  float T2[4];
  #pragma unroll
  for (int i = 0; i < 4; ++i)
    T2[i] = __fadd_rn(__fadd_rn(L[i], L[i+8]), __fadd_rn(L[i+4], L[i+12]));
  nrm[row] = __fadd_rn(__fadd_rn(T2[0], T2[2]), __fadd_rn(T2[1], T2[3]));
}

// ---------------- feature self-distance: numpy einsum contig_outstride0_two, AVX512 ----------------
__global__ __launch_bounds__(256) void dist_feat_kernel(const float* fb, const float* nrm, float* D){
  __shared__ float Aq[16*PAD];
  __shared__ float Bm[16*PAD];
  int nb = blockIdx.y*16, mb = blockIdx.x*16;
  int t = threadIdx.x;
  {
    int r = t >> 4, seg = (t & 15) << 3;
    const float* an = fb + (size_t)(nb + r)*CIN + seg;
    const float* bm = fb + (size_t)(mb + r)*CIN + seg;
    #pragma unroll
    for (int j = 0; j < 8; ++j){ Aq[r*PAD + seg + j] = an[j]; Bm[r*PAD + seg + j] = bm[j]; }
  }
  __syncthreads();
  int ty = t >> 4, tx = t & 15;
  const float* qa = &Aq[ty*PAD];
  const float* ma = &Bm[tx*PAD];
  float P[16];
  #pragma unroll
  for (int l = 0; l < 16; ++l) P[l] = __fmul_rn(qa[48+l], ma[48+l]);
  #pragma unroll
  for (int l = 0; l < 16; ++l) P[l] = __fmaf_rn(qa[32+l], ma[32+l], P[l]);
  #pragma unroll
  for (int l = 0; l < 16; ++l) P[l] = __fmaf_rn(qa[16+l], ma[16+l], P[l]);
  #pragma unroll
  for (int l = 0; l < 16; ++l) P[l] = __fmaf_rn(qa[ 0+l], ma[ 0+l], P[l]);
  #pragma unroll
  for (int l = 0; l < 16; ++l) P[l] = __fmaf_rn(qa[112+l], ma[112+l], P[l]);
  #pragma unroll
  for (int l = 0; l < 16; ++l) P[l] = __fmaf_rn(qa[96+l], ma[96+l], P[l]);
  #pragma unroll
  for (int l = 0; l < 16; ++l) P[l] = __fmaf_rn(qa[80+l], ma[80+l], P[l]);
  #pragma unroll
  for (int l = 0; l < 16; ++l) P[l] = __fmaf_rn(qa[64+l], ma[64+l], P[l]);
  float T2[4];
  #pragma unroll
  for (int i = 0; i < 4; ++i)
    T2[i] = __fadd_rn(__fadd_rn(P[i], P[i+8]), __fadd_rn(P[i+4], P[i+12]));
  float dot = __fadd_rn(__fadd_rn(T2[0], T2[2]), __fadd_rn(T2[1], T2[3]));
  int n = nb + ty, m = mb + tx;
  D[(size_t)n*NPTS + m] = __fsub_rn(__fadd_rn(nrm[n], nrm[m]), __fmul_rn(2.f, dot));
}

__global__ __launch_bounds__(64) void topk_row_kernel(const float* D, int* idx_out){
  int n = blockIdx.x;
  int lane = threadIdx.x;
  const float* src = D + (size_t)n*NPTS;
  unsigned long long k64[32];
  #pragma unroll
  for (int i = 0; i < 32; ++i){
    int m = i*64 + lane;
    k64[i] = dist_key(src[m], m);
  }
  wave_topk32(k64, lane, idx_out + (size_t)n*KNN);
}

// ---------------- generic tiled GEMM: C[*,N] = A[*,K] @ B[K,N] + bias[N], fp32 acc ----------------
__global__ __launch_bounds__(256) void gemm_tiled(const float* A, int lda, const float* B, int ldb,
                                                  const float* bias, float* C, int ldc, int K){
  __shared__ float As[64*17];
  __shared__ float Bs[16*65];
  int nb = blockIdx.x*64, mb = blockIdx.y*64;
  int tx = threadIdx.x & 15, ty = threadIdx.x >> 4;
  float acc[4][4] = {};
  for (int kt = 0; kt < K; kt += 16){
    {
      int r = threadIdx.x >> 2, c4 = (threadIdx.x & 3) << 2;
      const float* ap = A + (size_t)(mb + r)*lda + kt + c4;
      #pragma unroll
      for (int j = 0; j < 4; ++j) As[r*17+c4+j] = ap[j];
    }
    {
      int r = threadIdx.x >> 4, c4 = (threadIdx.x & 15) << 2;
      const float* bp = B + (size_t)(kt + r)*ldb + nb + c4;
      #pragma unroll
      for (int j = 0; j < 4; ++j) Bs[r*65+c4+j] = bp[j];
    }
    __syncthreads();
    #pragma unroll
    for (int kk = 0; kk < 16; ++kk){
      float a[4], bv[4];
      #pragma unroll
      for (int i = 0; i < 4; ++i) a[i] = As[(ty*4+i)*17+kk];
      #pragma unroll
      for (int j = 0; j < 4; ++j) bv[j] = Bs[kk*65 + tx*4 + j];
      #pragma unroll
      for (int i = 0; i < 4; ++i)
        #pragma unroll
        for (int j = 0; j < 4; ++j) acc[i][j] += a[i]*bv[j];
    }
    __syncthreads();
  }
  #pragma unroll
  for (int i = 0; i < 4; ++i){
    int row = mb + ty*4 + i;
    #pragma unroll
    for (int j = 0; j < 4; ++j){
      int col = nb + tx*4 + j;
      C[(size_t)row*ldc + col] = acc[i][j] + bias[col];
    }
  }
}

// ---------------- attention for one branch: Xb[8192][1024] = [q|k|v|res] fp32 ----------------
__global__ __launch_bounds__(256) void attn_kernel(const float* Xb, const int* ip, float* ctx){
  int bn = blockIdx.x;
  int b  = bn >> 11;
  int c  = threadIdx.x;
  __shared__ int jr[KNN];
  if (c < KNN) jr[c] = (b << 11) + ip[(size_t)bn*KNN + c];
  __syncthreads();
  float qv = Xb[(size_t)bn*1024 + c];
  float e[KNN];
  float mx = -3.4e38f;
  #pragma unroll
  for (int k = 0; k < KNN; ++k){
    float kv = Xb[(size_t)jr[k]*1024 + 256 + c];
    e[k] = (qv - kv) * 0.0625f;     // / sqrt(256)
    mx = fmaxf(mx, e[k]);
  }
  float s = 0.f;
  #pragma unroll
  for (int k = 0; k < KNN; ++k) s += __expf(e[k] - mx);
  float inv = 1.f / s;
  float best = -3.4e38f;
  #pragma unroll
  for (int k = 0; k < KNN; ++k){
    float vv  = Xb[(size_t)jr[k]*1024 + 512 + c];
    float att = __expf(e[k] - mx)*inv - 1.0f;   // softmax minus its (==1) sum
    best = fmaxf(best, att*vv);
  }
  ctx[(size_t)bn*COUT + c] = best;
}

// ---------------- BatchNorm stats (deterministic two-stage) ----------------
__global__ __launch_bounds__(256) void bn_stats_partial(const float* Xp, int ld, float* partial){
  int p = blockIdx.x, c = threadIdx.x;
  float s = 0.f, s2 = 0.f;
  for (int r = 0; r < 256; ++r){
    float v = Xp[(size_t)(p*256 + r)*ld + c];
    s += v; s2 += v*v;
  }
  partial[p*512 + c]       = s;
  partial[p*512 + 256 + c] = s2;
}

__global__ __launch_bounds__(256) void bn_stats_final(const float* partial, float* stats){
  int c = threadIdx.x;
  float s = 0.f, s2 = 0.f;
  for (int p = 0; p < 32; ++p){ s += partial[p*512 + c]; s2 += partial[p*512 + 256 + c]; }
  float mean = s * (1.f/8192.f);
  float var  = s2 * (1.f/8192.f) - mean*mean;   // biased var
  stats[c]       = mean;
  stats[256 + c] = 1.f / sqrtf(var + 1e-5f);
}

// ---------------- m_i = leaky(bn_res(res)) + leaky(bn_ffn(F)); write Mmat[:, i*256:] ----------------
__global__ __launch_bounds__(256) void build_m_kernel(const float* Xb, const float* F,
    const float* sR, const float* sF,
    const float* gR, const float* bR, const float* gF, const float* bF,
    float* Mcol){
  int bn = blockIdx.x, c = threadIdx.x;
  float r  = Xb[(size_t)bn*1024 + 768 + c];
  float rv = gR[c] * (r - sR[c]) * sR[256+c] + bR[c];
  rv = lrelu(rv);
  float f  = F[(size_t)bn*COUT + c];
  float fv = gF[c] * (f - sF[c]) * sF[256+c] + bF[c];
  fv = lrelu(fv);
  Mcol[(size_t)bn*512 + c] = rv + fv;
}

__global__ __launch_bounds__(256) void final_kernel(const float* Y, const float* stats,
                                                    const float* g, const float* be, float* out){
  int bn = blockIdx.x, c = threadIdx.x;
  float y = Y[(size_t)bn*COUT + c];
  float v = g[c] * (y - stats[c]) * stats[256+c] + be[c];
  out[(size_t)bn*COUT + c] = lrelu(v);   // fp32 output
}

extern "C" void kernel_launch(void* const* d_in, const int* in_sizes, int n_in,
                              void* d_out, int out_size, void* d_ws, size_t ws_size,
                              hipStream_t stream){
  const float* xyz      = (const float*)d_in[0];
  const float* base_xyz = (const float*)d_in[1];
  const float* feature  = (const float*)d_in[2];
  const float* qW = (const float*)d_in[3];
  const float* qb = (const float*)d_in[4];
  const float* kW = (const float*)d_in[5];
  const float* kb = (const float*)d_in[6];
  const float* vW = (const float*)d_in[7];
  const float* vb = (const float*)d_in[8];
  const float* rW = (const float*)d_in[9];
  const float* rb = (const float*)d_in[10];
  const float* res_gamma = (const float*)d_in[11];
  const float* res_beta  = (const float*)d_in[12];
  const float* ffnW = (const float*)d_in[13];
  const float* ffnb = (const float*)d_in[14];
  const float* ffn_gamma = (const float*)d_in[15];
  const float* ffn_beta  = (const float*)d_in[16];
  const float* fcW = (const float*)d_in[17];
  const float* fcb = (const float*)d_in[18];
  const float* fc_gamma = (const float*)d_in[19];
  const float* fc_beta  = (const float*)d_in[20];
  float* out = (float*)d_out;

  // ---- workspace plan (~67 MB) ----
  char* ws = (char*)d_ws;
  size_t o = 0;
  auto alloc = [&](size_t bytes)->char*{
    char* p = ws + o;
    o += (bytes + 255) & ~(size_t)255;
    return p;
  };
  int*   idx0   = (int*)  alloc((size_t)ROWS*KNN*4);        // 1 MB
  int*   idx1   = (int*)  alloc((size_t)ROWS*KNN*4);        // 1 MB
  float* nrm    = (float*)alloc((size_t)ROWS*4);            // 32 KB
  float* Wcat   = (float*)alloc((size_t)CIN*2048*4);        // 1 MB
  float* bcat   = (float*)alloc((size_t)2048*4);            // 8 KB
  float* stats  = (float*)alloc((size_t)5*512*4);
  float* partial= (float*)alloc((size_t)32*512*4);
  char*  R1     = alloc((size_t)ROWS*1024*4);               // 32 MB: Dbuf (16MB) -> Xb fp32
  float* Mmat   = (float*)alloc((size_t)ROWS*512*4);        // 16 MB
  char*  R3     = alloc((size_t)ROWS*COUT*4);               //  8 MB: ctx -> Y
  float* F      = (float*)alloc((size_t)ROWS*COUT*4);       //  8 MB
  float* Dbuf = (float*)R1;
  float* Xb   = (float*)R1;
  float* ctx  = (float*)R3;
  float* Y    = (float*)R3;

  pack_w_kernel<<<(CIN*2048)/256, 256, 0, stream>>>(qW,kW,vW,rW,qb,kb,vb,rb,Wcat,bcat);
  knn_xyz_kernel<<<ROWS, 64, 0, stream>>>(xyz, base_xyz, idx0);
  rownorm_kernel<<<ROWS/256, 256, 0, stream>>>(feature, nrm);

  // per-batch feature-distance (numpy AVX512-faithful fp32) + wave-parallel top-k
  for (int b = 0; b < 4; ++b){
    const float* fb = feature + (size_t)b*NPTS*CIN;
    dist_feat_kernel<<<dim3(NPTS/16, NPTS/16), 256, 0, stream>>>(
        fb, nrm + (size_t)b*NPTS, Dbuf);
    topk_row_kernel<<<NPTS, 64, 0, stream>>>(Dbuf, idx1 + (size_t)b*NPTS*KNN);
  }

  // two transformer branches, sequential (Xb/ctx/F regions reused)
  for (int i = 0; i < 2; ++i){
    gemm_tiled<<<dim3(1024/64, ROWS/64), 256, 0, stream>>>(
        feature, CIN, Wcat + (size_t)i*1024, 2048, bcat + (size_t)i*1024, Xb, 1024, CIN);

    attn_kernel<<<ROWS, 256, 0, stream>>>(Xb, (i == 0 ? idx0 : idx1), ctx);

    bn_stats_partial<<<32, 256, 0, stream>>>(Xb + 768, 1024, partial);
    bn_stats_final<<<1, 256, 0, stream>>>(partial, stats + (size_t)i*512);

    gemm_tiled<<<dim3(COUT/64, ROWS/64), 256, 0, stream>>>(
        ctx, COUT, ffnW + (size_t)i*COUT*COUT, COUT, ffnb + (size_t)i*COUT, F, COUT, COUT);
    bn_stats_partial<<<32, 256, 0, stream>>>(F, COUT, partial);
    bn_stats_final<<<1, 256, 0, stream>>>(partial, stats + (size_t)(2+i)*512);

    build_m_kernel<<<ROWS, 256, 0, stream>>>(Xb, F,
        stats + (size_t)i*512, stats + (size_t)(2+i)*512,
        res_gamma + (size_t)i*COUT, res_beta + (size_t)i*COUT,
        ffn_gamma + (size_t)i*COUT, ffn_beta + (size_t)i*COUT,
        Mmat + (size_t)i*COUT);
  }

  // fc: Y = Mmat[8192][512] @ fcW[512][256] + fcb
  gemm_tiled<<<dim3(COUT/64, ROWS/64), 256, 0, stream>>>(
      Mmat, 512, fcW, COUT, fcb, Y, COUT, 512);
  bn_stats_partial<<<32, 256, 0, stream>>>(Y, COUT, partial);
  bn_stats_final<<<1, 256, 0, stream>>>(partial, stats + 4*512);

  final_kernel<<<ROWS, 256, 0, stream>>>(Y, stats + 4*512, fc_gamma, fc_beta, out);
}

// Round 10
// 967.595 us; speedup vs baseline: 4.8287x; 1.0589x over previous
//
#include <hip/hip_runtime.h>
#include <hip/hip_bf16.h>

typedef __hip_bfloat16 bf16;

#define ROWS 8192   // B*N
#define NPTS 2048
#define CIN  128
#define COUT 256
#define KNN  32
#define PAD  132    // 16-row LDS tile leading dim

__device__ inline float lrelu(float x){ return x >= 0.f ? x : 0.2f*x; }

// ---------------- weight packing: Wcat[128][2048] = [q0|k0|v0|r0|q1|k1|v1|r1] ----------------
__global__ __launch_bounds__(256) void pack_w_kernel(
    const float* qW, const float* kW, const float* vW, const float* rW,
    const float* qb, const float* kb, const float* vb, const float* rb,
    float* Wcat, float* bcat){
  int t = blockIdx.x*256 + threadIdx.x;     // 0 .. 128*2048-1
  int r = t >> 11, c = t & 2047;
  int g = c >> 8, i = g >> 2, tt = g & 3, cc = c & 255;
  const float* W = (tt==0?qW: tt==1?kW: tt==2?vW: rW) + (size_t)i*CIN*COUT;
  Wcat[t] = W[r*COUT + cc];
  if (r == 0){
    const float* bb = (tt==0?qb: tt==1?kb: tt==2?vb: rb) + i*COUT;
    bcat[c] = bb[cc];
  }
}

// ---------------- wave-parallel top-32: keys in registers, no scratch (R8 form) ----------------
// key = monotone-uint(d) << 32 | m  -> lexicographic (d, idx) min == lax.top_k tie semantics
__device__ inline unsigned long long dist_key(float d, int m){
  unsigned u = __float_as_uint(d);
  u = (u & 0x80000000u) ? ~u : (u | 0x80000000u);
  return ((unsigned long long)u << 32) | (unsigned)m;
}

__device__ inline void wave_topk32(unsigned long long* k64, int lane, int* out){
  for (int r = 0; r < KNN; ++r){
    unsigned long long m = k64[0];
    #pragma unroll
    for (int j = 1; j < 32; ++j) m = (k64[j] < m) ? k64[j] : m;
    #pragma unroll
    for (int s = 1; s < 64; s <<= 1){
      unsigned long long o = __shfl_xor(m, s, 64);
      m = (o < m) ? o : m;
    }
    int wm = (int)(unsigned)(m & 0xFFFFFFFFu);
    if ((wm & 63) == lane){
      int jw = wm >> 6;
      #pragma unroll
      for (int j = 0; j < 32; ++j) if (j == jw) k64[j] = ~0ull;
    }
    if (lane == 0) out[r] = wm;
  }
}

// ---------------- xyz KNN: numpy scalar path (R8 form: 64 threads, LDS row) ----------------
__global__ __launch_bounds__(64) void knn_xyz_kernel(const float* xyz, const float* base, int* idx_out){
  __shared__ float drow[NPTS];
  int bid = blockIdx.x;           // b*2048+n
  int b = bid >> 11;
  int lane = threadIdx.x;
  float q0 = xyz[(size_t)bid*3+0];
  float q1 = xyz[(size_t)bid*3+1];
  float q2 = xyz[(size_t)bid*3+2];
  float qq = __fadd_rn(__fadd_rn(__fmul_rn(q0,q0), __fmul_rn(q1,q1)), __fmul_rn(q2,q2));
  const float* bb = base + (size_t)b*NPTS*3;
  for (int m = lane; m < NPTS; m += 64){
    float p0 = bb[m*3+0], p1 = bb[m*3+1], p2 = bb[m*3+2];
    float pp = __fadd_rn(__fadd_rn(__fmul_rn(p0,p0), __fmul_rn(p1,p1)), __fmul_rn(p2,p2));
    float dot = __fmul_rn(q0,p0);
    dot = __fadd_rn(dot, __fmul_rn(q1,p1));
    dot = __fadd_rn(dot, __fmul_rn(q2,p2));
    drow[m] = __fsub_rn(__fadd_rn(qq, pp), __fmul_rn(2.f, dot));
  }
  __syncthreads();
  unsigned long long k64[32];
  #pragma unroll
  for (int i = 0; i < 32; ++i){
    int m = i*64 + lane;
    k64[i] = dist_key(drow[m], m);
  }
  wave_topk32(k64, lane, idx_out + (size_t)bid*KNN);
}

// ---------------- feature norms: numpy SIMD pairwise block (AVX512, 8 vec accumulators) ----------------
__global__ __launch_bounds__(256) void rownorm_kernel(const float* feat, float* nrm){
  int row = blockIdx.x*256 + threadIdx.x;
  const float* f = feat + (size_t)row*CIN;
  float L[16];
  #pragma unroll
  for (int l = 0; l < 16; ++l){
    float x0 = __fmul_rn(f[l],     f[l]);
    float x1 = __fmul_rn(f[16+l],  f[16+l]);
    float x2 = __fmul_rn(f[32+l],  f[32+l]);
    float x3 = __fmul_rn(f[48+l],  f[48+l]);
    float x4 = __fmul_rn(f[64+l],  f[64+l]);
    float x5 = __fmul_rn(f[80+l],  f[80+l]);
    float x6 = __fmul_rn(f[96+l],  f[96+l]);
    float x7 = __fmul_rn(f[112+l], f[112+l]);
    L[l] = __fadd_rn(
        __fadd_rn(__fadd_rn(x0,x1), __fadd_rn(x2,x3)),
        __fadd_rn(__fadd_rn(x4,x5), __fadd_rn(x6,x7)));
  }
  float T2[4];
  #pragma unroll
  for (int i = 0; i < 4; ++i)
    T2[i] = __fadd_rn(__fadd_rn(L[i], L[i+8]), __fadd_rn(L[i+4], L[i+12]));
  nrm[row] = __fadd_rn(__fadd_rn(T2[0], T2[2]), __fadd_rn(T2[1], T2[3]));
}

// ---------------- feature self-distance: numpy einsum contig_outstride0_two, AVX512 ----------------
__global__ __launch_bounds__(256) void dist_feat_kernel(const float* fb, const float* nrm, float* D){
  __shared__ float Aq[16*PAD];
  __shared__ float Bm[16*PAD];
  int nb = blockIdx.y*16, mb = blockIdx.x*16;
  int t = threadIdx.x;
  {
    int r = t >> 4, seg = (t & 15) << 3;
    const float* an = fb + (size_t)(nb + r)*CIN + seg;
    const float* bm = fb + (size_t)(mb + r)*CIN + seg;
    #pragma unroll
    for (int j = 0; j < 8; ++j){ Aq[r*PAD + seg + j] = an[j]; Bm[r*PAD + seg + j] = bm[j]; }
  }
  __syncthreads();
  int ty = t >> 4, tx = t & 15;
  const float* qa = &Aq[ty*PAD];
  const float* ma = &Bm[tx*PAD];
  float P[16];
  #pragma unroll
  for (int l = 0; l < 16; ++l) P[l] = __fmul_rn(qa[48+l], ma[48+l]);
  #pragma unroll
  for (int l = 0; l < 16; ++l) P[l] = __fmaf_rn(qa[32+l], ma[32+l], P[l]);
  #pragma unroll
  for (int l = 0; l < 16; ++l) P[l] = __fmaf_rn(qa[16+l], ma[16+l], P[l]);
  #pragma unroll
  for (int l = 0; l < 16; ++l) P[l] = __fmaf_rn(qa[ 0+l], ma[ 0+l], P[l]);
  #pragma unroll
  for (int l = 0; l < 16; ++l) P[l] = __fmaf_rn(qa[112+l], ma[112+l], P[l]);
  #pragma unroll
  for (int l = 0; l < 16; ++l) P[l] = __fmaf_rn(qa[96+l], ma[96+l], P[l]);
  #pragma unroll
  for (int l = 0; l < 16; ++l) P[l] = __fmaf_rn(qa[80+l], ma[80+l], P[l]);
  #pragma unroll
  for (int l = 0; l < 16; ++l) P[l] = __fmaf_rn(qa[64+l], ma[64+l], P[l]);
  float T2[4];
  #pragma unroll
  for (int i = 0; i < 4; ++i)
    T2[i] = __fadd_rn(__fadd_rn(P[i], P[i+8]), __fadd_rn(P[i+4], P[i+12]));
  float dot = __fadd_rn(__fadd_rn(T2[0], T2[2]), __fadd_rn(T2[1], T2[3]));
  int n = nb + ty, m = mb + tx;
  D[(size_t)n*NPTS + m] = __fsub_rn(__fadd_rn(nrm[n], nrm[m]), __fmul_rn(2.f, dot));
}

// ---------------- feature top-k (R8 form: 64 threads, 1 row/block) ----------------
__global__ __launch_bounds__(64) void topk_row_kernel(const float* D, int* idx_out){
  int n = blockIdx.x;
  int lane = threadIdx.x;
  const float* src = D + (size_t)n*NPTS;
  unsigned long long k64[32];
  #pragma unroll
  for (int i = 0; i < 32; ++i){
    int m = i*64 + lane;
    k64[i] = dist_key(src[m], m);
  }
  wave_topk32(k64, lane, idx_out + (size_t)n*KNN);
}

// ---------------- generic tiled GEMM: C[*,N] = A[*,K] @ B[K,N] + bias[N], fp32 acc ----------------
// As stored kk-major (like Bs) so both fragment reads are ds_read_b128.
__global__ __launch_bounds__(256) void gemm_tiled(const float* A, int lda, const float* B, int ldb,
                                                  const float* bias, float* C, int ldc, int K){
  __shared__ float As[16*65];
  __shared__ float Bs[16*65];
  int nb = blockIdx.x*64, mb = blockIdx.y*64;
  int tx = threadIdx.x & 15, ty = threadIdx.x >> 4;
  float acc[4][4] = {};
  for (int kt = 0; kt < K; kt += 16){
    {
      int r = threadIdx.x >> 2, c4 = (threadIdx.x & 3) << 2;
      const float* ap = A + (size_t)(mb + r)*lda + kt + c4;
      #pragma unroll
      for (int j = 0; j < 4; ++j) As[(c4+j)*65 + r] = ap[j];
    }
    {
      int r = threadIdx.x >> 4, c4 = (threadIdx.x & 15) << 2;
      const float* bp = B + (size_t)(kt + r)*ldb + nb + c4;
      #pragma unroll
      for (int j = 0; j < 4; ++j) Bs[r*65+c4+j] = bp[j];
    }
    __syncthreads();
    #pragma unroll
    for (int kk = 0; kk < 16; ++kk){
      float a[4], bv[4];
      #pragma unroll
      for (int i = 0; i < 4; ++i) a[i] = As[kk*65 + ty*4 + i];
      #pragma unroll
      for (int j = 0; j < 4; ++j) bv[j] = Bs[kk*65 + tx*4 + j];
      #pragma unroll
      for (int i = 0; i < 4; ++i)
        #pragma unroll
        for (int j = 0; j < 4; ++j) acc[i][j] += a[i]*bv[j];
    }
    __syncthreads();
  }
  #pragma unroll
  for (int i = 0; i < 4; ++i){
    int row = mb + ty*4 + i;
    #pragma unroll
    for (int j = 0; j < 4; ++j){
      int col = nb + tx*4 + j;
      C[(size_t)row*ldc + col] = acc[i][j] + bias[col];
    }
  }
}

// ---------------- attention: float2/lane, 2 rows per 256-block ----------------
__global__ __launch_bounds__(256) void attn_kernel(const float* Xb, const int* ip, float* ctx){
  int local = threadIdx.x & 127;   // 0..127: channel pair index
  int r     = threadIdx.x >> 7;    // row within block
  int bn    = blockIdx.x*2 + r;
  int b     = bn >> 11;
  __shared__ int jr[2][KNN];
  if (local < KNN) jr[r][local] = (b << 11) + ip[(size_t)bn*KNN + local];
  __syncthreads();
  const float2* X2 = (const float2*)Xb;    // row stride = 512 float2
  float2 qv = X2[(size_t)bn*512 + local];
  float2 e[KNN];
  float mx_x = -3.4e38f, mx_y = -3.4e38f;
  #pragma unroll
  for (int k = 0; k < KNN; ++k){
    float2 kv = X2[(size_t)jr[r][k]*512 + 128 + local];
    e[k].x = (qv.x - kv.x) * 0.0625f;
    e[k].y = (qv.y - kv.y) * 0.0625f;
    mx_x = fmaxf(mx_x, e[k].x);
    mx_y = fmaxf(mx_y, e[k].y);
  }
  float s_x = 0.f, s_y = 0.f;
  #pragma unroll
  for (int k = 0; k < KNN; ++k){
    s_x += __expf(e[k].x - mx_x);
    s_y += __expf(e[k].y - mx_y);
  }
  float inv_x = 1.f / s_x, inv_y = 1.f / s_y;
  float best_x = -3.4e38f, best_y = -3.4e38f;
  #pragma unroll
  for (int k = 0; k < KNN; ++k){
    float2 vv = X2[(size_t)jr[r][k]*512 + 256 + local];
    float ax = __expf(e[k].x - mx_x)*inv_x - 1.0f;
    float ay = __expf(e[k].y - mx_y)*inv_y - 1.0f;
    best_x = fmaxf(best_x, ax*vv.x);
    best_y = fmaxf(best_y, ay*vv.y);
  }
  float2* C2 = (float2*)ctx;
  float2 o; o.x = best_x; o.y = best_y;
  C2[(size_t)bn*128 + local] = o;
}

// ---------------- BatchNorm stats (deterministic two-stage) ----------------
__global__ __launch_bounds__(256) void bn_stats_partial(const float* Xp, int ld, float* partial){
  int p = blockIdx.x, c = threadIdx.x;
  float s = 0.f, s2 = 0.f;
  for (int r = 0; r < 256; ++r){
    float v = Xp[(size_t)(p*256 + r)*ld + c];
    s += v; s2 += v*v;
  }
  partial[p*512 + c]       = s;
  partial[p*512 + 256 + c] = s2;
}

__global__ __launch_bounds__(256) void bn_stats_final(const float* partial, float* stats){
  int c = threadIdx.x;
  float s = 0.f, s2 = 0.f;
  for (int p = 0; p < 32; ++p){ s += partial[p*512 + c]; s2 += partial[p*512 + 256 + c]; }
  float mean = s * (1.f/8192.f);
  float var  = s2 * (1.f/8192.f) - mean*mean;   // biased var
  stats[c]       = mean;
  stats[256 + c] = 1.f / sqrtf(var + 1e-5f);
}

// ---------------- m_i = leaky(bn_res(res)) + leaky(bn_ffn(F)); write Mmat[:, i*256:] ----------------
__global__ __launch_bounds__(256) void build_m_kernel(const float* Xb, const float* F,
    const float* sR, const float* sF,
    const float* gR, const float* bR, const float* gF, const float* bF,
    float* Mcol){
  int bn = blockIdx.x, c = threadIdx.x;
  float r  = Xb[(size_t)bn*1024 + 768 + c];
  float rv = gR[c] * (r - sR[c]) * sR[256+c] + bR[c];
  rv = lrelu(rv);
  float f  = F[(size_t)bn*COUT + c];
  float fv = gF[c] * (f - sF[c]) * sF[256+c] + bF[c];
  fv = lrelu(fv);
  Mcol[(size_t)bn*512 + c] = rv + fv;
}

__global__ __launch_bounds__(256) void final_kernel(const float* Y, const float* stats,
                                                    const float* g, const float* be, float* out){
  int bn = blockIdx.x, c = threadIdx.x;
  float y = Y[(size_t)bn*COUT + c];
  float v = g[c] * (y - stats[c]) * stats[256+c] + be[c];
  out[(size_t)bn*COUT + c] = lrelu(v);   // fp32 output
}

extern "C" void kernel_launch(void* const* d_in, const int* in_sizes, int n_in,
                              void* d_out, int out_size, void* d_ws, size_t ws_size,
                              hipStream_t stream){
  const float* xyz      = (const float*)d_in[0];
  const float* base_xyz = (const float*)d_in[1];
  const float* feature  = (const float*)d_in[2];
  const float* qW = (const float*)d_in[3];
  const float* qb = (const float*)d_in[4];
  const float* kW = (const float*)d_in[5];
  const float* kb = (const float*)d_in[6];
  const float* vW = (const float*)d_in[7];
  const float* vb = (const float*)d_in[8];
  const float* rW = (const float*)d_in[9];
  const float* rb = (const float*)d_in[10];
  const float* res_gamma = (const float*)d_in[11];
  const float* res_beta  = (const float*)d_in[12];
  const float* ffnW = (const float*)d_in[13];
  const float* ffnb = (const float*)d_in[14];
  const float* ffn_gamma = (const float*)d_in[15];
  const float* ffn_beta  = (const float*)d_in[16];
  const float* fcW = (const float*)d_in[17];
  const float* fcb = (const float*)d_in[18];
  const float* fc_gamma = (const float*)d_in[19];
  const float* fc_beta  = (const float*)d_in[20];
  float* out = (float*)d_out;

  // ---- workspace plan (~67 MB) ----
  char* ws = (char*)d_ws;
  size_t o = 0;
  auto alloc = [&](size_t bytes)->char*{
    char* p = ws + o;
    o += (bytes + 255) & ~(size_t)255;
    return p;
  };
  int*   idx0   = (int*)  alloc((size_t)ROWS*KNN*4);        // 1 MB
  int*   idx1   = (int*)  alloc((size_t)ROWS*KNN*4);        // 1 MB
  float* nrm    = (float*)alloc((size_t)ROWS*4);            // 32 KB
  float* Wcat   = (float*)alloc((size_t)CIN*2048*4);        // 1 MB
  float* bcat   = (float*)alloc((size_t)2048*4);            // 8 KB
  float* stats  = (float*)alloc((size_t)5*512*4);
  float* partial= (float*)alloc((size_t)32*512*4);
  char*  R1     = alloc((size_t)ROWS*1024*4);               // 32 MB: Dbuf (16MB) -> Xb fp32
  float* Mmat   = (float*)alloc((size_t)ROWS*512*4);        // 16 MB
  char*  R3     = alloc((size_t)ROWS*COUT*4);               //  8 MB: ctx -> Y
  float* F      = (float*)alloc((size_t)ROWS*COUT*4);       //  8 MB
  float* Dbuf = (float*)R1;
  float* Xb   = (float*)R1;
  float* ctx  = (float*)R3;
  float* Y    = (float*)R3;

  pack_w_kernel<<<(CIN*2048)/256, 256, 0, stream>>>(qW,kW,vW,rW,qb,kb,vb,rb,Wcat,bcat);
  knn_xyz_kernel<<<ROWS, 64, 0, stream>>>(xyz, base_xyz, idx0);
  rownorm_kernel<<<ROWS/256, 256, 0, stream>>>(feature, nrm);

  // per-batch feature-distance (numpy AVX512-faithful fp32) + wave-parallel top-k
  for (int b = 0; b < 4; ++b){
    const float* fb = feature + (size_t)b*NPTS*CIN;
    dist_feat_kernel<<<dim3(NPTS/16, NPTS/16), 256, 0, stream>>>(
        fb, nrm + (size_t)b*NPTS, Dbuf);
    topk_row_kernel<<<NPTS, 64, 0, stream>>>(Dbuf, idx1 + (size_t)b*NPTS*KNN);
  }

  // two transformer branches, sequential (Xb/ctx/F regions reused)
  for (int i = 0; i < 2; ++i){
    gemm_tiled<<<dim3(1024/64, ROWS/64), 256, 0, stream>>>(
        feature, CIN, Wcat + (size_t)i*1024, 2048, bcat + (size_t)i*1024, Xb, 1024, CIN);

    attn_kernel<<<ROWS/2, 256, 0, stream>>>(Xb, (i == 0 ? idx0 : idx1), ctx);

    bn_stats_partial<<<32, 256, 0, stream>>>(Xb + 768, 1024, partial);
    bn_stats_final<<<1, 256, 0, stream>>>(partial, stats + (size_t)i*512);

    gemm_tiled<<<dim3(COUT/64, ROWS/64), 256, 0, stream>>>(
        ctx, COUT, ffnW + (size_t)i*COUT*COUT, COUT, ffnb + (size_t)i*COUT, F, COUT, COUT);
    bn_stats_partial<<<32, 256, 0, stream>>>(F, COUT, partial);
    bn_stats_final<<<1, 256, 0, stream>>>(partial, stats + (size_t)(2+i)*512);

    build_m_kernel<<<ROWS, 256, 0, stream>>>(Xb, F,
        stats + (size_t)i*512, stats + (size_t)(2+i)*512,
        res_gamma + (size_t)i*COUT, res_beta + (size_t)i*COUT,
        ffn_gamma + (size_t)i*COUT, ffn_beta + (size_t)i*COUT,
        Mmat + (size_t)i*COUT);
  }

  // fc: Y = Mmat[8192][512] @ fcW[512][256] + fcb
  gemm_tiled<<<dim3(COUT/64, ROWS/64), 256, 0, stream>>>(
      Mmat, 512, fcW, COUT, fcb, Y, COUT, 512);
  bn_stats_partial<<<32, 256, 0, stream>>>(Y, COUT, partial);
  bn_stats_final<<<1, 256, 0, stream>>>(partial, stats + 4*512);

  final_kernel<<<ROWS, 256, 0, stream>>>(Y, stats + 4*512, fc_gamma, fc_beta, out);
}

// Round 11
// 824.073 us; speedup vs baseline: 5.6697x; 1.1742x over previous
//
#include <hip/hip_runtime.h>
#include <hip/hip_bf16.h>

typedef __hip_bfloat16 bf16;
typedef __attribute__((ext_vector_type(8))) short short8;
typedef __attribute__((ext_vector_type(4))) float f32x4;

#define ROWS 8192   // B*N
#define NPTS 2048
#define CIN  128
#define COUT 256
#define KNN  32
#define PAD  132    // 16-row LDS tile leading dim (dist_feat)

__device__ inline float lrelu(float x){ return x >= 0.f ? x : 0.2f*x; }
__device__ inline unsigned short f2bf(float x){
  bf16 h = __float2bfloat16(x);
  return *(unsigned short*)&h;
}

// ---------------- one-time weight prep: bcat fp32 + WT_x[2048][128] bf16 (transposed) ----------------
__global__ __launch_bounds__(256) void pack_wt_x(
    const float* qW, const float* kW, const float* vW, const float* rW,
    const float* qb, const float* kb, const float* vb, const float* rb,
    unsigned short* WT, float* bcat){
  int t = blockIdx.x*256 + threadIdx.x;   // 0 .. 2048*128-1
  int c = t >> 7, r = t & 127;            // c = global col, r = k index
  int g = c >> 8, i = g >> 2, tt = g & 3, cc = c & 255;
  const float* W = (tt==0?qW: tt==1?kW: tt==2?vW: rW) + (size_t)i*CIN*COUT;
  WT[t] = f2bf(W[r*COUT + cc]);
  if (r == 0){
    const float* bb = (tt==0?qb: tt==1?kb: tt==2?vb: rb) + i*COUT;
    bcat[c] = bb[cc];
  }
}

__global__ __launch_bounds__(256) void pack_wt_ffn(const float* ffnW, unsigned short* WT){
  int t = blockIdx.x*256 + threadIdx.x;   // 0 .. 2*256*256-1
  int i = t >> 16, n = (t >> 8) & 255, k = t & 255;
  WT[t] = f2bf(ffnW[(size_t)i*65536 + k*256 + n]);
}

__global__ __launch_bounds__(256) void pack_wt_fc(const float* fcW, unsigned short* WT){
  int t = blockIdx.x*256 + threadIdx.x;   // 0 .. 256*512-1
  int n = t >> 9, k = t & 511;
  WT[t] = f2bf(fcW[(size_t)k*256 + n]);
}

__global__ __launch_bounds__(256) void cvt_bf16_kernel(const float* src, unsigned short* dst){
  int t = blockIdx.x*256 + threadIdx.x;
  dst[t] = f2bf(src[t]);
}

// ---------------- wave-parallel top-32 (frozen R10 form) ----------------
__device__ inline unsigned long long dist_key(float d, int m){
  unsigned u = __float_as_uint(d);
  u = (u & 0x80000000u) ? ~u : (u | 0x80000000u);
  return ((unsigned long long)u << 32) | (unsigned)m;
}

__device__ inline void wave_topk32(unsigned long long* k64, int lane, int* out){
  for (int r = 0; r < KNN; ++r){
    unsigned long long m = k64[0];
    #pragma unroll
    for (int j = 1; j < 32; ++j) m = (k64[j] < m) ? k64[j] : m;
    #pragma unroll
    for (int s = 1; s < 64; s <<= 1){
      unsigned long long o = __shfl_xor(m, s, 64);
      m = (o < m) ? o : m;
    }
    int wm = (int)(unsigned)(m & 0xFFFFFFFFu);
    if ((wm & 63) == lane){
      int jw = wm >> 6;
      #pragma unroll
      for (int j = 0; j < 32; ++j) if (j == jw) k64[j] = ~0ull;
    }
    if (lane == 0) out[r] = wm;
  }
}

// ---------------- xyz KNN (frozen R10 form: numpy-faithful fp32, bit-exact) ----------------
__global__ __launch_bounds__(64) void knn_xyz_kernel(const float* xyz, const float* base, int* idx_out){
  __shared__ float drow[NPTS];
  int bid = blockIdx.x;
  int b = bid >> 11;
  int lane = threadIdx.x;
  float q0 = xyz[(size_t)bid*3+0];
  float q1 = xyz[(size_t)bid*3+1];
  float q2 = xyz[(size_t)bid*3+2];
  float qq = __fadd_rn(__fadd_rn(__fmul_rn(q0,q0), __fmul_rn(q1,q1)), __fmul_rn(q2,q2));
  const float* bb = base + (size_t)b*NPTS*3;
  for (int m = lane; m < NPTS; m += 64){
    float p0 = bb[m*3+0], p1 = bb[m*3+1], p2 = bb[m*3+2];
    float pp = __fadd_rn(__fadd_rn(__fmul_rn(p0,p0), __fmul_rn(p1,p1)), __fmul_rn(p2,p2));
    float dot = __fmul_rn(q0,p0);
    dot = __fadd_rn(dot, __fmul_rn(q1,p1));
    dot = __fadd_rn(dot, __fmul_rn(q2,p2));
    drow[m] = __fsub_rn(__fadd_rn(qq, pp), __fmul_rn(2.f, dot));
  }
  __syncthreads();
  unsigned long long k64[32];
  #pragma unroll
  for (int i = 0; i < 32; ++i){
    int m = i*64 + lane;
    k64[i] = dist_key(drow[m], m);
  }
  wave_topk32(k64, lane, idx_out + (size_t)bid*KNN);
}

// ---------------- feature norms (frozen: numpy AVX512 pairwise) ----------------
__global__ __launch_bounds__(256) void rownorm_kernel(const float* feat, float* nrm){
  int row = blockIdx.x*256 + threadIdx.x;
  const float* f = feat + (size_t)row*CIN;
  float L[16];
  #pragma unroll
  for (int l = 0; l < 16; ++l){
    float x0 = __fmul_rn(f[l],     f[l]);
    float x1 = __fmul_rn(f[16+l],  f[16+l]);
    float x2 = __fmul_rn(f[32+l],  f[32+l]);
    float x3 = __fmul_rn(f[48+l],  f[48+l]);
    float x4 = __fmul_rn(f[64+l],  f[64+l]);
    float x5 = __fmul_rn(f[80+l],  f[80+l]);
    float x6 = __fmul_rn(f[96+l],  f[96+l]);
    float x7 = __fmul_rn(f[112+l], f[112+l]);
    L[l] = __fadd_rn(
        __fadd_rn(__fadd_rn(x0,x1), __fadd_rn(x2,x3)),
        __fadd_rn(__fadd_rn(x4,x5), __fadd_rn(x6,x7)));
  }
  float T2[4];
  #pragma unroll
  for (int i = 0; i < 4; ++i)
    T2[i] = __fadd_rn(__fadd_rn(L[i], L[i+8]), __fadd_rn(L[i+4], L[i+12]));
  nrm[row] = __fadd_rn(__fadd_rn(T2[0], T2[2]), __fadd_rn(T2[1], T2[3]));
}

// ---------------- feature self-distance (frozen: numpy einsum AVX512 bit-exact) ----------------
__global__ __launch_bounds__(256) void dist_feat_kernel(const float* fb, const float* nrm, float* D){
  __shared__ float Aq[16*PAD];
  __shared__ float Bm[16*PAD];
  int nb = blockIdx.y*16, mb = blockIdx.x*16;
  int t = threadIdx.x;
  {
    int r = t >> 4, seg = (t & 15) << 3;
    const float* an = fb + (size_t)(nb + r)*CIN + seg;
    const float* bm = fb + (size_t)(mb + r)*CIN + seg;
    #pragma unroll
    for (int j = 0; j < 8; ++j){ Aq[r*PAD + seg + j] = an[j]; Bm[r*PAD + seg + j] = bm[j]; }
  }
  __syncthreads();
  int ty = t >> 4, tx = t & 15;
  const float* qa = &Aq[ty*PAD];
  const float* ma = &Bm[tx*PAD];
  float P[16];
  #pragma unroll
  for (int l = 0; l < 16; ++l) P[l] = __fmul_rn(qa[48+l], ma[48+l]);
  #pragma unroll
  for (int l = 0; l < 16; ++l) P[l] = __fmaf_rn(qa[32+l], ma[32+l], P[l]);
  #pragma unroll
  for (int l = 0; l < 16; ++l) P[l] = __fmaf_rn(qa[16+l], ma[16+l], P[l]);
  #pragma unroll
  for (int l = 0; l < 16; ++l) P[l] = __fmaf_rn(qa[ 0+l], ma[ 0+l], P[l]);
  #pragma unroll
  for (int l = 0; l < 16; ++l) P[l] = __fmaf_rn(qa[112+l], ma[112+l], P[l]);
  #pragma unroll
  for (int l = 0; l < 16; ++l) P[l] = __fmaf_rn(qa[96+l], ma[96+l], P[l]);
  #pragma unroll
  for (int l = 0; l < 16; ++l) P[l] = __fmaf_rn(qa[80+l], ma[80+l], P[l]);
  #pragma unroll
  for (int l = 0; l < 16; ++l) P[l] = __fmaf_rn(qa[64+l], ma[64+l], P[l]);
  float T2[4];
  #pragma unroll
  for (int i = 0; i < 4; ++i)
    T2[i] = __fadd_rn(__fadd_rn(P[i], P[i+8]), __fadd_rn(P[i+4], P[i+12]));
  float dot = __fadd_rn(__fadd_rn(T2[0], T2[2]), __fadd_rn(T2[1], T2[3]));
  int n = nb + ty, m = mb + tx;
  D[(size_t)n*NPTS + m] = __fsub_rn(__fadd_rn(nrm[n], nrm[m]), __fmul_rn(2.f, dot));
}

// ---------------- feature top-k (frozen R10 form) ----------------
__global__ __launch_bounds__(64) void topk_row_kernel(const float* D, int* idx_out){
  int n = blockIdx.x;
  int lane = threadIdx.x;
  const float* src = D + (size_t)n*NPTS;
  unsigned long long k64[32];
  #pragma unroll
  for (int i = 0; i < 32; ++i){
    int m = i*64 + lane;
    k64[i] = dist_key(src[m], m);
  }
  wave_topk32(k64, lane, idx_out + (size_t)n*KNN);
}

// ---------------- MFMA GEMM: C[M,N] = bf16(A)[M,K] @ bf16(B^T)[N,K] + bias, fp32 acc ----------------
// 64x64 tile, 4 waves; v_mfma_f32_16x16x32_bf16.
// A-frag: [m=lane&15][k=quad*8+j]; B^T-frag: [n=lane&15][k=quad*8+j];
// C/D: row = quad*4+reg (M), col = lane&15 (N)  [m91-verified layout]
__global__ __launch_bounds__(256) void mfma_gemm(const unsigned short* __restrict__ A,
                                                 const unsigned short* __restrict__ Bt,
                                                 const float* __restrict__ bias,
                                                 float* __restrict__ C,
                                                 int N, int K){
  __shared__ unsigned short As[64*40];   // stride 40 shorts: 2-way bank alias max (free)
  __shared__ unsigned short Bs[64*40];
  int nb = blockIdx.x*64, mb = blockIdx.y*64;
  int t = threadIdx.x;
  int wave = t >> 6, lane = t & 63;
  int m16 = lane & 15, quad = lane >> 4;
  f32x4 acc[4];
  #pragma unroll
  for (int s = 0; s < 4; ++s) acc[s] = (f32x4){0.f, 0.f, 0.f, 0.f};
  int srow = t >> 2, skseg = (t & 3) << 3;
  for (int kt = 0; kt < K; kt += 32){
    __syncthreads();
    *(uint4*)&As[srow*40 + skseg] = *(const uint4*)&A [(size_t)(mb + srow)*K + kt + skseg];
    *(uint4*)&Bs[srow*40 + skseg] = *(const uint4*)&Bt[(size_t)(nb + srow)*K + kt + skseg];
    __syncthreads();
    short8 a = *(const short8*)&As[(wave*16 + m16)*40 + quad*8];
    #pragma unroll
    for (int s = 0; s < 4; ++s){
      short8 b = *(const short8*)&Bs[(s*16 + m16)*40 + quad*8];
      acc[s] = __builtin_amdgcn_mfma_f32_16x16x32_bf16(a, b, acc[s], 0, 0, 0);
    }
  }
  #pragma unroll
  for (int s = 0; s < 4; ++s){
    int col = nb + s*16 + m16;
    float bv = bias[col];
    #pragma unroll
    for (int r = 0; r < 4; ++r){
      int row = mb + wave*16 + quad*4 + r;
      C[(size_t)row*N + col] = acc[s][r] + bv;
    }
  }
}

// ---------------- attention: float2/lane, 2 rows per 256-block; bf16 ctx out ----------------
__global__ __launch_bounds__(256) void attn_kernel(const float* Xb, const int* ip, unsigned short* ctx){
  int local = threadIdx.x & 127;
  int r     = threadIdx.x >> 7;
  int bn    = blockIdx.x*2 + r;
  int b     = bn >> 11;
  __shared__ int jr[2][KNN];
  if (local < KNN) jr[r][local] = (b << 11) + ip[(size_t)bn*KNN + local];
  __syncthreads();
  const float2* X2 = (const float2*)Xb;    // row stride = 512 float2
  float2 qv = X2[(size_t)bn*512 + local];
  float2 e[KNN];
  float mx_x = -3.4e38f, mx_y = -3.4e38f;
  #pragma unroll
  for (int k = 0; k < KNN; ++k){
    float2 kv = X2[(size_t)jr[r][k]*512 + 128 + local];
    e[k].x = (qv.x - kv.x) * 0.0625f;
    e[k].y = (qv.y - kv.y) * 0.0625f;
    mx_x = fmaxf(mx_x, e[k].x);
    mx_y = fmaxf(mx_y, e[k].y);
  }
  float s_x = 0.f, s_y = 0.f;
  #pragma unroll
  for (int k = 0; k < KNN; ++k){
    s_x += __expf(e[k].x - mx_x);
    s_y += __expf(e[k].y - mx_y);
  }
  float inv_x = 1.f / s_x, inv_y = 1.f / s_y;
  float best_x = -3.4e38f, best_y = -3.4e38f;
  #pragma unroll
  for (int k = 0; k < KNN; ++k){
    float2 vv = X2[(size_t)jr[r][k]*512 + 256 + local];
    float ax = __expf(e[k].x - mx_x)*inv_x - 1.0f;
    float ay = __expf(e[k].y - mx_y)*inv_y - 1.0f;
    best_x = fmaxf(best_x, ax*vv.x);
    best_y = fmaxf(best_y, ay*vv.y);
  }
  ushort2 o; o.x = f2bf(best_x); o.y = f2bf(best_y);
  ((ushort2*)ctx)[(size_t)bn*128 + local] = o;
}

// ---------------- BatchNorm stats (deterministic two-stage) ----------------
__global__ __launch_bounds__(256) void bn_stats_partial(const float* Xp, int ld, float* partial){
  int p = blockIdx.x, c = threadIdx.x;
  float s = 0.f, s2 = 0.f;
  for (int r = 0; r < 256; ++r){
    float v = Xp[(size_t)(p*256 + r)*ld + c];
    s += v; s2 += v*v;
  }
  partial[p*512 + c]       = s;
  partial[p*512 + 256 + c] = s2;
}

__global__ __launch_bounds__(256) void bn_stats_final(const float* partial, float* stats){
  int c = threadIdx.x;
  float s = 0.f, s2 = 0.f;
  for (int p = 0; p < 32; ++p){ s += partial[p*512 + c]; s2 += partial[p*512 + 256 + c]; }
  float mean = s * (1.f/8192.f);
  float var  = s2 * (1.f/8192.f) - mean*mean;   // biased var
  stats[c]       = mean;
  stats[256 + c] = 1.f / sqrtf(var + 1e-5f);
}

// ---------------- m_i = leaky(bn_res(res)) + leaky(bn_ffn(F)) -> Mmat bf16 [:, i*256:] ----------------
__global__ __launch_bounds__(256) void build_m_kernel(const float* Xb, const float* F,
    const float* sR, const float* sF,
    const float* gR, const float* bR, const float* gF, const float* bF,
    unsigned short* Mcol){
  int bn = blockIdx.x, c = threadIdx.x;
  float r  = Xb[(size_t)bn*1024 + 768 + c];
  float rv = gR[c] * (r - sR[c]) * sR[256+c] + bR[c];
  rv = lrelu(rv);
  float f  = F[(size_t)bn*COUT + c];
  float fv = gF[c] * (f - sF[c]) * sF[256+c] + bF[c];
  fv = lrelu(fv);
  Mcol[(size_t)bn*512 + c] = f2bf(rv + fv);
}

__global__ __launch_bounds__(256) void final_kernel(const float* Y, const float* stats,
                                                    const float* g, const float* be, float* out){
  int bn = blockIdx.x, c = threadIdx.x;
  float y = Y[(size_t)bn*COUT + c];
  float v = g[c] * (y - stats[c]) * stats[256+c] + be[c];
  out[(size_t)bn*COUT + c] = lrelu(v);
}

extern "C" void kernel_launch(void* const* d_in, const int* in_sizes, int n_in,
                              void* d_out, int out_size, void* d_ws, size_t ws_size,
                              hipStream_t stream){
  const float* xyz      = (const float*)d_in[0];
  const float* base_xyz = (const float*)d_in[1];
  const float* feature  = (const float*)d_in[2];
  const float* qW = (const float*)d_in[3];
  const float* qb = (const float*)d_in[4];
  const float* kW = (const float*)d_in[5];
  const float* kb = (const float*)d_in[6];
  const float* vW = (const float*)d_in[7];
  const float* vb = (const float*)d_in[8];
  const float* rW = (const float*)d_in[9];
  const float* rb = (const float*)d_in[10];
  const float* res_gamma = (const float*)d_in[11];
  const float* res_beta  = (const float*)d_in[12];
  const float* ffnW = (const float*)d_in[13];
  const float* ffnb = (const float*)d_in[14];
  const float* ffn_gamma = (const float*)d_in[15];
  const float* ffn_beta  = (const float*)d_in[16];
  const float* fcW = (const float*)d_in[17];
  const float* fcb = (const float*)d_in[18];
  const float* fc_gamma = (const float*)d_in[19];
  const float* fc_beta  = (const float*)d_in[20];
  float* out = (float*)d_out;

  // ---- workspace plan (~65 MB) ----
  char* ws = (char*)d_ws;
  size_t o = 0;
  auto alloc = [&](size_t bytes)->char*{
    char* p = ws + o;
    o += (bytes + 255) & ~(size_t)255;
    return p;
  };
  int*            idx0    = (int*)           alloc((size_t)ROWS*KNN*4);
  int*            idx1    = (int*)           alloc((size_t)ROWS*KNN*4);
  float*          nrm     = (float*)         alloc((size_t)ROWS*4);
  float*          bcat    = (float*)         alloc((size_t)2048*4);
  unsigned short* WT_x    = (unsigned short*)alloc((size_t)2048*CIN*2);     // [2048][128]
  unsigned short* WT_ffn  = (unsigned short*)alloc((size_t)2*COUT*COUT*2);  // [2][256][256]
  unsigned short* WT_fc   = (unsigned short*)alloc((size_t)COUT*512*2);     // [256][512]
  unsigned short* feat_bf = (unsigned short*)alloc((size_t)ROWS*CIN*2);     // 2 MB
  float*          stats   = (float*)         alloc((size_t)5*512*4);
  float*          partial = (float*)         alloc((size_t)32*512*4);
  char*           R1      = alloc((size_t)ROWS*1024*4);                     // 32 MB: Dbuf -> Xb fp32
  unsigned short* ctx_bf  = (unsigned short*)alloc((size_t)ROWS*COUT*2);    // 4 MB
  unsigned short* Mmat_bf = (unsigned short*)alloc((size_t)ROWS*512*2);     // 8 MB
  float*          F       = (float*)         alloc((size_t)ROWS*COUT*4);    // 8 MB
  float*          Y       = (float*)         alloc((size_t)ROWS*COUT*4);    // 8 MB
  float* Dbuf = (float*)R1;
  float* Xb   = (float*)R1;

  // one-time prep
  pack_wt_x<<<(2048*CIN)/256, 256, 0, stream>>>(qW,kW,vW,rW,qb,kb,vb,rb,WT_x,bcat);
  pack_wt_ffn<<<(2*COUT*COUT)/256, 256, 0, stream>>>(ffnW, WT_ffn);
  pack_wt_fc<<<(COUT*512)/256, 256, 0, stream>>>(fcW, WT_fc);
  cvt_bf16_kernel<<<(ROWS*CIN)/256, 256, 0, stream>>>(feature, feat_bf);

  knn_xyz_kernel<<<ROWS, 64, 0, stream>>>(xyz, base_xyz, idx0);
  rownorm_kernel<<<ROWS/256, 256, 0, stream>>>(feature, nrm);

  // per-batch feature-distance (numpy-faithful fp32, frozen) + wave-parallel top-k
  for (int b = 0; b < 4; ++b){
    const float* fb = feature + (size_t)b*NPTS*CIN;
    dist_feat_kernel<<<dim3(NPTS/16, NPTS/16), 256, 0, stream>>>(
        fb, nrm + (size_t)b*NPTS, Dbuf);
    topk_row_kernel<<<NPTS, 64, 0, stream>>>(Dbuf, idx1 + (size_t)b*NPTS*KNN);
  }

  // two transformer branches, sequential
  for (int i = 0; i < 2; ++i){
    // Xb[8192][1024] = feat_bf @ WT_x[i]^T  (MFMA, fp32 out)
    mfma_gemm<<<dim3(1024/64, ROWS/64), 256, 0, stream>>>(
        feat_bf, WT_x + (size_t)i*1024*CIN, bcat + (size_t)i*1024, Xb, 1024, CIN);

    attn_kernel<<<ROWS/2, 256, 0, stream>>>(Xb, (i == 0 ? idx0 : idx1), ctx_bf);

    bn_stats_partial<<<32, 256, 0, stream>>>(Xb + 768, 1024, partial);
    bn_stats_final<<<1, 256, 0, stream>>>(partial, stats + (size_t)i*512);

    // F = ctx @ ffnW_i + ffnb_i  (MFMA)
    mfma_gemm<<<dim3(COUT/64, ROWS/64), 256, 0, stream>>>(
        ctx_bf, WT_ffn + (size_t)i*COUT*COUT, ffnb + (size_t)i*COUT, F, COUT, COUT);
    bn_stats_partial<<<32, 256, 0, stream>>>(F, COUT, partial);
    bn_stats_final<<<1, 256, 0, stream>>>(partial, stats + (size_t)(2+i)*512);

    build_m_kernel<<<ROWS, 256, 0, stream>>>(Xb, F,
        stats + (size_t)i*512, stats + (size_t)(2+i)*512,
        res_gamma + (size_t)i*COUT, res_beta + (size_t)i*COUT,
        ffn_gamma + (size_t)i*COUT, ffn_beta + (size_t)i*COUT,
        Mmat_bf + (size_t)i*COUT);
  }

  // fc: Y = Mmat[8192][512] @ fcW + fcb  (MFMA)
  mfma_gemm<<<dim3(COUT/64, ROWS/64), 256, 0, stream>>>(
      Mmat_bf, WT_fc, fcb, Y, COUT, 512);
  bn_stats_partial<<<32, 256, 0, stream>>>(Y, COUT, partial);
  bn_stats_final<<<1, 256, 0, stream>>>(partial, stats + 4*512);

  final_kernel<<<ROWS, 256, 0, stream>>>(Y, stats + 4*512, fc_gamma, fc_beta, out);
}

// Round 12
// 688.552 us; speedup vs baseline: 6.7856x; 1.1968x over previous
//
#include <hip/hip_runtime.h>
#include <hip/hip_bf16.h>

typedef __hip_bfloat16 bf16;
typedef __attribute__((ext_vector_type(8))) short short8;
typedef __attribute__((ext_vector_type(4))) float f32x4;

#define ROWS 8192   // B*N
#define NPTS 2048
#define CIN  128
#define COUT 256
#define KNN  32
#define PAD  132    // 16-row LDS tile leading dim (dist_feat)

__device__ inline float lrelu(float x){ return x >= 0.f ? x : 0.2f*x; }
__device__ inline unsigned short f2bf(float x){
  bf16 h = __float2bfloat16(x);
  return *(unsigned short*)&h;
}
__device__ inline float bf2f(unsigned short u){ return __uint_as_float((unsigned)u << 16); }
__device__ inline void stc(float* p, float v){ *p = v; }
__device__ inline void stc(unsigned short* p, float v){ *p = f2bf(v); }

// ---------------- fused one-time prep: WT_x, bcat, WT_ffn, WT_fc, feat_bf ----------------
#define N_WTX   (2048*CIN)          // 262144
#define N_WFFN  (2*COUT*COUT)       // 131072
#define N_WFC   (COUT*512)          // 131072
#define N_FEAT  (ROWS*CIN)          // 1048576
__global__ __launch_bounds__(256) void pack_all(
    const float* qW, const float* kW, const float* vW, const float* rW,
    const float* qb, const float* kb, const float* vb, const float* rb,
    const float* ffnW, const float* fcW, const float* feature,
    unsigned short* WT_x, float* bcat, unsigned short* WT_ffn,
    unsigned short* WT_fc, unsigned short* feat_bf){
  int t = blockIdx.x*256 + threadIdx.x;
  if (t < N_WTX){
    int c = t >> 7, r = t & 127;
    int g = c >> 8, i = g >> 2, tt = g & 3, cc = c & 255;
    const float* W = (tt==0?qW: tt==1?kW: tt==2?vW: rW) + (size_t)i*CIN*COUT;
    WT_x[t] = f2bf(W[r*COUT + cc]);
    if (r == 0){
      const float* bb = (tt==0?qb: tt==1?kb: tt==2?vb: rb) + i*COUT;
      bcat[c] = bb[cc];
    }
  } else if (t < N_WTX + N_WFFN){
    int u = t - N_WTX;
    int i = u >> 16, n = (u >> 8) & 255, k = u & 255;
    WT_ffn[u] = f2bf(ffnW[(size_t)i*65536 + k*256 + n]);
  } else if (t < N_WTX + N_WFFN + N_WFC){
    int u = t - N_WTX - N_WFFN;
    int n = u >> 9, k = u & 511;
    WT_fc[u] = f2bf(fcW[(size_t)k*256 + n]);
  } else {
    int u = t - N_WTX - N_WFFN - N_WFC;
    feat_bf[u] = f2bf(feature[u]);
  }
}

// ---------------- wave-parallel top-32 (frozen) ----------------
__device__ inline unsigned long long dist_key(float d, int m){
  unsigned u = __float_as_uint(d);
  u = (u & 0x80000000u) ? ~u : (u | 0x80000000u);
  return ((unsigned long long)u << 32) | (unsigned)m;
}

__device__ inline void wave_topk32(unsigned long long* k64, int lane, int* out){
  for (int r = 0; r < KNN; ++r){
    unsigned long long m = k64[0];
    #pragma unroll
    for (int j = 1; j < 32; ++j) m = (k64[j] < m) ? k64[j] : m;
    #pragma unroll
    for (int s = 1; s < 64; s <<= 1){
      unsigned long long o = __shfl_xor(m, s, 64);
      m = (o < m) ? o : m;
    }
    int wm = (int)(unsigned)(m & 0xFFFFFFFFu);
    if ((wm & 63) == lane){
      int jw = wm >> 6;
      #pragma unroll
      for (int j = 0; j < 32; ++j) if (j == jw) k64[j] = ~0ull;
    }
    if (lane == 0) out[r] = wm;
  }
}

// ---------------- xyz KNN (frozen: numpy-faithful fp32, bit-exact) ----------------
__global__ __launch_bounds__(64) void knn_xyz_kernel(const float* xyz, const float* base, int* idx_out){
  __shared__ float drow[NPTS];
  int bid = blockIdx.x;
  int b = bid >> 11;
  int lane = threadIdx.x;
  float q0 = xyz[(size_t)bid*3+0];
  float q1 = xyz[(size_t)bid*3+1];
  float q2 = xyz[(size_t)bid*3+2];
  float qq = __fadd_rn(__fadd_rn(__fmul_rn(q0,q0), __fmul_rn(q1,q1)), __fmul_rn(q2,q2));
  const float* bb = base + (size_t)b*NPTS*3;
  for (int m = lane; m < NPTS; m += 64){
    float p0 = bb[m*3+0], p1 = bb[m*3+1], p2 = bb[m*3+2];
    float pp = __fadd_rn(__fadd_rn(__fmul_rn(p0,p0), __fmul_rn(p1,p1)), __fmul_rn(p2,p2));
    float dot = __fmul_rn(q0,p0);
    dot = __fadd_rn(dot, __fmul_rn(q1,p1));
    dot = __fadd_rn(dot, __fmul_rn(q2,p2));
    drow[m] = __fsub_rn(__fadd_rn(qq, pp), __fmul_rn(2.f, dot));
  }
  __syncthreads();
  unsigned long long k64[32];
  #pragma unroll
  for (int i = 0; i < 32; ++i){
    int m = i*64 + lane;
    k64[i] = dist_key(drow[m], m);
  }
  wave_topk32(k64, lane, idx_out + (size_t)bid*KNN);
}

// ---------------- feature norms (frozen: numpy AVX512 pairwise) ----------------
__global__ __launch_bounds__(256) void rownorm_kernel(const float* feat, float* nrm){
  int row = blockIdx.x*256 + threadIdx.x;
  const float* f = feat + (size_t)row*CIN;
  float L[16];
  #pragma unroll
  for (int l = 0; l < 16; ++l){
    float x0 = __fmul_rn(f[l],     f[l]);
    float x1 = __fmul_rn(f[16+l],  f[16+l]);
    float x2 = __fmul_rn(f[32+l],  f[32+l]);
    float x3 = __fmul_rn(f[48+l],  f[48+l]);
    float x4 = __fmul_rn(f[64+l],  f[64+l]);
    float x5 = __fmul_rn(f[80+l],  f[80+l]);
    float x6 = __fmul_rn(f[96+l],  f[96+l]);
    float x7 = __fmul_rn(f[112+l], f[112+l]);
    L[l] = __fadd_rn(
        __fadd_rn(__fadd_rn(x0,x1), __fadd_rn(x2,x3)),
        __fadd_rn(__fadd_rn(x4,x5), __fadd_rn(x6,x7)));
  }
  float T2[4];
  #pragma unroll
  for (int i = 0; i < 4; ++i)
    T2[i] = __fadd_rn(__fadd_rn(L[i], L[i+8]), __fadd_rn(L[i+4], L[i+12]));
  nrm[row] = __fadd_rn(__fadd_rn(T2[0], T2[2]), __fadd_rn(T2[1], T2[3]));
}

// ---------------- feature self-distance (frozen: numpy einsum AVX512 bit-exact) ----------------
__global__ __launch_bounds__(256) void dist_feat_kernel(const float* fb, const float* nrm, float* D){
  __shared__ float Aq[16*PAD];
  __shared__ float Bm[16*PAD];
  int nb = blockIdx.y*16, mb = blockIdx.x*16;
  int t = threadIdx.x;
  {
    int r = t >> 4, seg = (t & 15) << 3;
    const float* an = fb + (size_t)(nb + r)*CIN + seg;
    const float* bm = fb + (size_t)(mb + r)*CIN + seg;
    #pragma unroll
    for (int j = 0; j < 8; ++j){ Aq[r*PAD + seg + j] = an[j]; Bm[r*PAD + seg + j] = bm[j]; }
  }
  __syncthreads();
  int ty = t >> 4, tx = t & 15;
  const float* qa = &Aq[ty*PAD];
  const float* ma = &Bm[tx*PAD];
  float P[16];
  #pragma unroll
  for (int l = 0; l < 16; ++l) P[l] = __fmul_rn(qa[48+l], ma[48+l]);
  #pragma unroll
  for (int l = 0; l < 16; ++l) P[l] = __fmaf_rn(qa[32+l], ma[32+l], P[l]);
  #pragma unroll
  for (int l = 0; l < 16; ++l) P[l] = __fmaf_rn(qa[16+l], ma[16+l], P[l]);
  #pragma unroll
  for (int l = 0; l < 16; ++l) P[l] = __fmaf_rn(qa[ 0+l], ma[ 0+l], P[l]);
  #pragma unroll
  for (int l = 0; l < 16; ++l) P[l] = __fmaf_rn(qa[112+l], ma[112+l], P[l]);
  #pragma unroll
  for (int l = 0; l < 16; ++l) P[l] = __fmaf_rn(qa[96+l], ma[96+l], P[l]);
  #pragma unroll
  for (int l = 0; l < 16; ++l) P[l] = __fmaf_rn(qa[80+l], ma[80+l], P[l]);
  #pragma unroll
  for (int l = 0; l < 16; ++l) P[l] = __fmaf_rn(qa[64+l], ma[64+l], P[l]);
  float T2[4];
  #pragma unroll
  for (int i = 0; i < 4; ++i)
    T2[i] = __fadd_rn(__fadd_rn(P[i], P[i+8]), __fadd_rn(P[i+4], P[i+12]));
  float dot = __fadd_rn(__fadd_rn(T2[0], T2[2]), __fadd_rn(T2[1], T2[3]));
  int n = nb + ty, m = mb + tx;
  D[(size_t)n*NPTS + m] = __fsub_rn(__fadd_rn(nrm[n], nrm[m]), __fmul_rn(2.f, dot));
}

// ---------------- feature top-k (frozen) ----------------
__global__ __launch_bounds__(64) void topk_row_kernel(const float* D, int* idx_out){
  int n = blockIdx.x;
  int lane = threadIdx.x;
  const float* src = D + (size_t)n*NPTS;
  unsigned long long k64[32];
  #pragma unroll
  for (int i = 0; i < 32; ++i){
    int m = i*64 + lane;
    k64[i] = dist_key(src[m], m);
  }
  wave_topk32(k64, lane, idx_out + (size_t)n*KNN);
}

// ---------------- MFMA GEMM (batched via grid.z): C = bf16(A)[M,K] @ bf16(B^T)[N,K] + bias ----------------
// 64x64 tile, 4 waves; v_mfma_f32_16x16x32_bf16; layouts m91-verified (R11 pass).
template<typename CT>
__global__ __launch_bounds__(256) void mfma_gemm(const unsigned short* __restrict__ A,
                                                 const unsigned short* __restrict__ Bt,
                                                 const float* __restrict__ bias,
                                                 CT* __restrict__ C, int N, int K,
                                                 size_t sA, size_t sB, size_t sBias, size_t sC){
  int z = blockIdx.z;
  A += (size_t)z*sA; Bt += (size_t)z*sB; bias += (size_t)z*sBias; C += (size_t)z*sC;
  __shared__ unsigned short As[64*40];   // stride 40 shorts: 2-way bank alias max (free)
  __shared__ unsigned short Bs[64*40];
  int nb = blockIdx.x*64, mb = blockIdx.y*64;
  int t = threadIdx.x;
  int wave = t >> 6, lane = t & 63;
  int m16 = lane & 15, quad = lane >> 4;
  f32x4 acc[4];
  #pragma unroll
  for (int s = 0; s < 4; ++s) acc[s] = (f32x4){0.f, 0.f, 0.f, 0.f};
  int srow = t >> 2, skseg = (t & 3) << 3;
  for (int kt = 0; kt < K; kt += 32){
    __syncthreads();
    *(uint4*)&As[srow*40 + skseg] = *(const uint4*)&A [(size_t)(mb + srow)*K + kt + skseg];
    *(uint4*)&Bs[srow*40 + skseg] = *(const uint4*)&Bt[(size_t)(nb + srow)*K + kt + skseg];
    __syncthreads();
    short8 a = *(const short8*)&As[(wave*16 + m16)*40 + quad*8];
    #pragma unroll
    for (int s = 0; s < 4; ++s){
      short8 b = *(const short8*)&Bs[(s*16 + m16)*40 + quad*8];
      acc[s] = __builtin_amdgcn_mfma_f32_16x16x32_bf16(a, b, acc[s], 0, 0, 0);
    }
  }
  #pragma unroll
  for (int s = 0; s < 4; ++s){
    int col = nb + s*16 + m16;
    float bv = bias[col];
    #pragma unroll
    for (int r = 0; r < 4; ++r){
      int row = mb + wave*16 + quad*4 + r;
      stc(&C[(size_t)row*N + col], acc[s][r] + bv);
    }
  }
}

// ---------------- attention: bf16 X [8192][2048], both branches via grid.y; ushort2 gathers ----------------
__global__ __launch_bounds__(256) void attn_kernel(const unsigned short* X,
                                                   const int* idx0, const int* idx1,
                                                   unsigned short* ctx){
  int i = blockIdx.y;
  const int* ip = (i == 0 ? idx0 : idx1);
  int local = threadIdx.x & 127;
  int r     = threadIdx.x >> 7;
  int bn    = blockIdx.x*2 + r;
  int b     = bn >> 11;
  __shared__ int jr[2][KNN];
  if (local < KNN) jr[r][local] = (b << 11) + ip[(size_t)bn*KNN + local];
  __syncthreads();
  const ushort2* X2 = (const ushort2*)X;   // row stride 1024 ushort2
  size_t boff = (size_t)i*512 + local;     // q at +0, k +128, v +256 (ushort2 units)
  ushort2 q2 = X2[(size_t)bn*1024 + boff];
  float qx = bf2f(q2.x), qy = bf2f(q2.y);
  float ex[KNN], ey[KNN];
  float mx = -3.4e38f, my = -3.4e38f;
  #pragma unroll
  for (int k = 0; k < KNN; ++k){
    ushort2 k2 = X2[(size_t)jr[r][k]*1024 + boff + 128];
    ex[k] = (qx - bf2f(k2.x)) * 0.0625f;
    ey[k] = (qy - bf2f(k2.y)) * 0.0625f;
    mx = fmaxf(mx, ex[k]);
    my = fmaxf(my, ey[k]);
  }
  float sx = 0.f, sy = 0.f;
  #pragma unroll
  for (int k = 0; k < KNN; ++k){
    sx += __expf(ex[k] - mx);
    sy += __expf(ey[k] - my);
  }
  float ix = 1.f / sx, iy = 1.f / sy;
  float bx = -3.4e38f, by = -3.4e38f;
  #pragma unroll
  for (int k = 0; k < KNN; ++k){
    ushort2 v2 = X2[(size_t)jr[r][k]*1024 + boff + 256];
    float ax = __expf(ex[k] - mx)*ix - 1.0f;
    float ay = __expf(ey[k] - my)*iy - 1.0f;
    bx = fmaxf(bx, ax*bf2f(v2.x));
    by = fmaxf(by, ay*bf2f(v2.y));
  }
  ushort2 o; o.x = f2bf(bx); o.y = f2bf(by);
  ((ushort2*)ctx)[((size_t)i*ROWS + bn)*128 + local] = o;
}

// ---------------- BatchNorm stats (deterministic two-stage, batched over branches) ----------------
__global__ __launch_bounds__(256) void bnx_partial(const unsigned short* X, float* partial){
  int p = blockIdx.x, i = blockIdx.y, c = threadIdx.x;
  const unsigned short* base = X + (size_t)i*1024 + 768 + c;
  float s = 0.f, s2 = 0.f;
  for (int r = 0; r < 256; ++r){
    float v = bf2f(base[(size_t)(p*256 + r)*2048]);
    s += v; s2 += v*v;
  }
  partial[((size_t)i*32 + p)*512 + c]       = s;
  partial[((size_t)i*32 + p)*512 + 256 + c] = s2;
}

__global__ __launch_bounds__(256) void bnf_partial(const unsigned short* F, float* partial){
  int p = blockIdx.x, i = blockIdx.y, c = threadIdx.x;
  const unsigned short* base = F + (size_t)i*ROWS*COUT + c;
  float s = 0.f, s2 = 0.f;
  for (int r = 0; r < 256; ++r){
    float v = bf2f(base[(size_t)(p*256 + r)*COUT]);
    s += v; s2 += v*v;
  }
  partial[((size_t)i*32 + p)*512 + c]       = s;
  partial[((size_t)i*32 + p)*512 + 256 + c] = s2;
}

__global__ __launch_bounds__(256) void bny_partial(const float* Y, float* partial){
  int p = blockIdx.x, c = threadIdx.x;
  float s = 0.f, s2 = 0.f;
  for (int r = 0; r < 256; ++r){
    float v = Y[(size_t)(p*256 + r)*COUT + c];
    s += v; s2 += v*v;
  }
  partial[p*512 + c]       = s;
  partial[p*512 + 256 + c] = s2;
}

__global__ __launch_bounds__(256) void bn_final2(const float* partial, float* stats){
  int i = blockIdx.y, c = threadIdx.x;
  partial += (size_t)i*32*512;
  stats   += (size_t)i*512;
  float s = 0.f, s2 = 0.f;
  for (int p = 0; p < 32; ++p){ s += partial[p*512 + c]; s2 += partial[p*512 + 256 + c]; }
  float mean = s * (1.f/8192.f);
  float var  = s2 * (1.f/8192.f) - mean*mean;   // biased var
  stats[c]       = mean;
  stats[256 + c] = 1.f / sqrtf(var + 1e-5f);
}

// ---------------- m_i = leaky(bn_res(res)) + leaky(bn_ffn(F)) -> Mmat bf16, both branches ----------------
__global__ __launch_bounds__(256) void build_m_kernel(const unsigned short* X, const unsigned short* F,
    const float* stats, const float* gR, const float* bR, const float* gF, const float* bF,
    unsigned short* M){
  int bn = blockIdx.x, c = threadIdx.x;
  #pragma unroll
  for (int i = 0; i < 2; ++i){
    float r  = bf2f(X[(size_t)bn*2048 + i*1024 + 768 + c]);
    float rv = gR[i*COUT+c] * (r - stats[i*512+c]) * stats[i*512+256+c] + bR[i*COUT+c];
    rv = lrelu(rv);
    float f  = bf2f(F[(size_t)i*ROWS*COUT + (size_t)bn*COUT + c]);
    float fv = gF[i*COUT+c] * (f - stats[(2+i)*512+c]) * stats[(2+i)*512+256+c] + bF[i*COUT+c];
    fv = lrelu(fv);
    M[(size_t)bn*512 + i*COUT + c] = f2bf(rv + fv);
  }
}

__global__ __launch_bounds__(256) void final_kernel(const float* Y, const float* stats,
                                                    const float* g, const float* be, float* out){
  int bn = blockIdx.x, c = threadIdx.x;
  float y = Y[(size_t)bn*COUT + c];
  float v = g[c] * (y - stats[c]) * stats[256+c] + be[c];
  out[(size_t)bn*COUT + c] = lrelu(v);
}

extern "C" void kernel_launch(void* const* d_in, const int* in_sizes, int n_in,
                              void* d_out, int out_size, void* d_ws, size_t ws_size,
                              hipStream_t stream){
  const float* xyz      = (const float*)d_in[0];
  const float* base_xyz = (const float*)d_in[1];
  const float* feature  = (const float*)d_in[2];
  const float* qW = (const float*)d_in[3];
  const float* qb = (const float*)d_in[4];
  const float* kW = (const float*)d_in[5];
  const float* kb = (const float*)d_in[6];
  const float* vW = (const float*)d_in[7];
  const float* vb = (const float*)d_in[8];
  const float* rW = (const float*)d_in[9];
  const float* rb = (const float*)d_in[10];
  const float* res_gamma = (const float*)d_in[11];
  const float* res_beta  = (const float*)d_in[12];
  const float* ffnW = (const float*)d_in[13];
  const float* ffnb = (const float*)d_in[14];
  const float* ffn_gamma = (const float*)d_in[15];
  const float* ffn_beta  = (const float*)d_in[16];
  const float* fcW = (const float*)d_in[17];
  const float* fcb = (const float*)d_in[18];
  const float* fc_gamma = (const float*)d_in[19];
  const float* fc_beta  = (const float*)d_in[20];
  float* out = (float*)d_out;

  // ---- workspace plan (~61 MB, region reuse) ----
  char* ws = (char*)d_ws;
  size_t o = 0;
  auto alloc = [&](size_t bytes)->char*{
    char* p = ws + o;
    o += (bytes + 255) & ~(size_t)255;
    return p;
  };
  int*            idx0    = (int*)           alloc((size_t)ROWS*KNN*4);
  int*            idx1    = (int*)           alloc((size_t)ROWS*KNN*4);
  float*          nrm     = (float*)         alloc((size_t)ROWS*4);
  float*          bcat    = (float*)         alloc((size_t)2048*4);
  unsigned short* WT_x    = (unsigned short*)alloc((size_t)2048*CIN*2);
  unsigned short* WT_ffn  = (unsigned short*)alloc((size_t)2*COUT*COUT*2);
  unsigned short* WT_fc   = (unsigned short*)alloc((size_t)COUT*512*2);
  unsigned short* feat_bf = (unsigned short*)alloc((size_t)ROWS*CIN*2);
  float*          stats   = (float*)         alloc((size_t)5*512*4);
  float*          partial = (float*)         alloc((size_t)2*32*512*4);
  char*           R1      = alloc((size_t)ROWS*2048*2);   // 32 MB: Dbuf fp32 (16MB) -> X bf16 [8192][2048]
  char*           R2      = alloc((size_t)ROWS*COUT*4);   //  8 MB: ctx_bf (8MB) -> Y fp32
  unsigned short* Mmat_bf = (unsigned short*)alloc((size_t)ROWS*512*2);   // 8 MB
  unsigned short* F_bf    = (unsigned short*)alloc((size_t)2*ROWS*COUT*2);// 8 MB
  float*          Dbuf = (float*)R1;
  unsigned short* X_bf = (unsigned short*)R1;
  unsigned short* ctx_bf = (unsigned short*)R2;
  float*          Y    = (float*)R2;

  // one-time prep (fused)
  pack_all<<<(N_WTX+N_WFFN+N_WFC+N_FEAT)/256, 256, 0, stream>>>(
      qW,kW,vW,rW,qb,kb,vb,rb, ffnW, fcW, feature, WT_x, bcat, WT_ffn, WT_fc, feat_bf);

  knn_xyz_kernel<<<ROWS, 64, 0, stream>>>(xyz, base_xyz, idx0);
  rownorm_kernel<<<ROWS/256, 256, 0, stream>>>(feature, nrm);

  // per-batch feature-distance (frozen bit-exact) + wave-parallel top-k
  for (int b = 0; b < 4; ++b){
    const float* fb = feature + (size_t)b*NPTS*CIN;
    dist_feat_kernel<<<dim3(NPTS/16, NPTS/16), 256, 0, stream>>>(
        fb, nrm + (size_t)b*NPTS, Dbuf);
    topk_row_kernel<<<NPTS, 64, 0, stream>>>(Dbuf, idx1 + (size_t)b*NPTS*KNN);
  }

  // X[8192][2048] bf16 = feat_bf @ WT_x^T, both branches in one launch
  mfma_gemm<unsigned short><<<dim3(2048/64, ROWS/64, 1), 256, 0, stream>>>(
      feat_bf, WT_x, bcat, X_bf, 2048, CIN, 0, 0, 0, 0);

  // attention: both branches, one launch
  attn_kernel<<<dim3(ROWS/2, 2), 256, 0, stream>>>(X_bf, idx0, idx1, ctx_bf);

  // res BN stats (both branches)
  bnx_partial<<<dim3(32, 2), 256, 0, stream>>>(X_bf, partial);
  bn_final2<<<dim3(1, 2), 256, 0, stream>>>(partial, stats);          // slots 0,1

  // ffn GEMM: F_bf[i] = ctx_bf[i] @ ffnW_i + ffnb_i  (batched grid.z=2)
  mfma_gemm<unsigned short><<<dim3(COUT/64, ROWS/64, 2), 256, 0, stream>>>(
      ctx_bf, WT_ffn, ffnb, F_bf, COUT, COUT,
      (size_t)ROWS*COUT, (size_t)COUT*COUT, COUT, (size_t)ROWS*COUT);

  bnf_partial<<<dim3(32, 2), 256, 0, stream>>>(F_bf, partial);
  bn_final2<<<dim3(1, 2), 256, 0, stream>>>(partial, stats + 2*512);  // slots 2,3

  build_m_kernel<<<ROWS, 256, 0, stream>>>(X_bf, F_bf, stats,
      res_gamma, res_beta, ffn_gamma, ffn_beta, Mmat_bf);

  // fc: Y = Mmat @ fcW + fcb  (ctx region dead -> Y)
  mfma_gemm<float><<<dim3(COUT/64, ROWS/64, 1), 256, 0, stream>>>(
      Mmat_bf, WT_fc, fcb, Y, COUT, 512, 0, 0, 0, 0);

  bny_partial<<<32, 256, 0, stream>>>(Y, partial);
  bn_final2<<<dim3(1, 1), 256, 0, stream>>>(partial, stats + 4*512);  // slot 4

  final_kernel<<<ROWS, 256, 0, stream>>>(Y, stats + 4*512, fc_gamma, fc_beta, out);
}